// Round 1
// baseline (7642.196 us; speedup 1.0000x reference)
//
#include <hip/hip_runtime.h>
#include <hip/hip_bf16.h>
#include <math.h>

// GPT-2-like forward: B=2,T=1024,D=768,H=12,L=6,V=32000,HD=64. All fp32.
static constexpr int Bv = 2, Tv = 1024, Dv = 768, Hv = 12, Lv = 6, Vv = 32000, HDv = 64;
static constexpr int MROWS = Bv * Tv;   // 2048

// ---------------- embedding: x[b,t,:] = wte[idx[b,t],:] + wpe[t,:] ----------
__global__ __launch_bounds__(256) void embed_kernel(const int* __restrict__ idx,
                                                    const float* __restrict__ wte,
                                                    const float* __restrict__ wpe,
                                                    float* __restrict__ x) {
  int i4 = blockIdx.x * 256 + threadIdx.x;          // over B*T*D/4
  int total = MROWS * Dv / 4;
  if (i4 >= total) return;
  int d4 = (i4 % (Dv / 4)) * 4;
  int bt = i4 / (Dv / 4);
  int t  = bt % Tv;
  int id = idx[bt];
  float4 a = *(const float4*)(wte + (size_t)id * Dv + d4);
  float4 p = *(const float4*)(wpe + (size_t)t  * Dv + d4);
  a.x += p.x; a.y += p.y; a.z += p.z; a.w += p.w;
  *(float4*)(x + (size_t)bt * Dv + d4) = a;
}

// ---------------- layernorm: one block (256 thr) per row of 768 -------------
__global__ __launch_bounds__(256) void ln_kernel(const float* __restrict__ x,
                                                 const float* __restrict__ w,
                                                 const float* __restrict__ b,
                                                 float* __restrict__ out) {
  int row = blockIdx.x;
  const float* xr = x + (size_t)row * Dv;
  int tid = threadIdx.x;
  float v0 = xr[tid], v1 = xr[tid + 256], v2 = xr[tid + 512];
  __shared__ float red[8];
  int wid = tid >> 6, lane = tid & 63;

  float s = v0 + v1 + v2;
  #pragma unroll
  for (int off = 1; off < 64; off <<= 1) s += __shfl_xor(s, off, 64);
  if (lane == 0) red[wid] = s;
  __syncthreads();
  s = red[0] + red[1] + red[2] + red[3];
  float mu = s * (1.0f / Dv);

  float d0 = v0 - mu, d1 = v1 - mu, d2 = v2 - mu;
  float q = d0 * d0 + d1 * d1 + d2 * d2;
  #pragma unroll
  for (int off = 1; off < 64; off <<= 1) q += __shfl_xor(q, off, 64);
  if (lane == 0) red[4 + wid] = q;
  __syncthreads();
  q = red[4] + red[5] + red[6] + red[7];
  float rs = rsqrtf(q * (1.0f / Dv) + 1e-5f);

  float* orow = out + (size_t)row * Dv;
  orow[tid]       = d0 * rs * w[tid]       + b[tid];
  orow[tid + 256] = d1 * rs * w[tid + 256] + b[tid + 256];
  orow[tid + 512] = d2 * rs * w[tid + 512] + b[tid + 512];
}

// ---------------- tiled fp32 GEMM: out = act(A@W + bias) (+resid) -----------
// A [M,K] row-major, W [K,N] row-major. BM=BN=64, BK=16, 256 thr, 4x4/thread.
// ACT: 0 = none, 1 = exact GELU. bias/resid may be nullptr.
template <int ACT>
__global__ __launch_bounds__(256) void gemm_kernel(const float* __restrict__ A,
                                                   const float* __restrict__ W,
                                                   const float* __restrict__ bias,
                                                   const float* __restrict__ resid,
                                                   float* __restrict__ out,
                                                   int M, int N, int K) {
  __shared__ __align__(16) float As[16][68];   // [k][m], padded stride
  __shared__ __align__(16) float Bs[16][64];   // [k][n]
  int t  = threadIdx.x;
  int tx = t & 15, ty = t >> 4;
  int m0 = blockIdx.y * 64, n0 = blockIdx.x * 64;

  int am  = t >> 2,        ak4 = (t & 3) * 4;   // A loader: row am, 4 cols
  int bk  = t >> 4,        bn4 = (t & 15) * 4;  // B loader: row bk, 4 cols
  const float* Aptr = A + (size_t)(m0 + am) * K + ak4;
  const float* Wptr = W + (size_t)bk * N + n0 + bn4;

  float acc[4][4] = {};
  for (int k0 = 0; k0 < K; k0 += 16) {
    float4 av = *(const float4*)(Aptr + k0);
    float4 wv = *(const float4*)(Wptr + (size_t)k0 * N);
    __syncthreads();
    As[ak4 + 0][am] = av.x;
    As[ak4 + 1][am] = av.y;
    As[ak4 + 2][am] = av.z;
    As[ak4 + 3][am] = av.w;
    *(float4*)&Bs[bk][bn4] = wv;
    __syncthreads();
    #pragma unroll
    for (int kk = 0; kk < 16; ++kk) {
      float4 a  = *(const float4*)&As[kk][ty * 4];
      float4 bv = *(const float4*)&Bs[kk][tx * 4];
      float ar[4] = {a.x, a.y, a.z, a.w};
      float br[4] = {bv.x, bv.y, bv.z, bv.w};
      #pragma unroll
      for (int i = 0; i < 4; ++i)
        #pragma unroll
        for (int j = 0; j < 4; ++j) acc[i][j] += ar[i] * br[j];
    }
  }

  int row = m0 + ty * 4, col = n0 + tx * 4;
  float bv4[4] = {0.f, 0.f, 0.f, 0.f};
  if (bias) {
    float4 bb = *(const float4*)(bias + col);
    bv4[0] = bb.x; bv4[1] = bb.y; bv4[2] = bb.z; bv4[3] = bb.w;
  }
  #pragma unroll
  for (int i = 0; i < 4; ++i) {
    float r[4];
    #pragma unroll
    for (int j = 0; j < 4; ++j) {
      float v = acc[i][j] + bv4[j];
      if (ACT == 1) v = 0.5f * v * (1.0f + erff(v * 0.70710678118f));
      r[j] = v;
    }
    if (resid) {
      float4 rr = *(const float4*)(resid + (size_t)(row + i) * N + col);
      r[0] += rr.x; r[1] += rr.y; r[2] += rr.z; r[3] += rr.w;
    }
    float4 o4 = make_float4(r[0], r[1], r[2], r[3]);
    *(float4*)(out + (size_t)(row + i) * N + col) = o4;
  }
}

// ---------------- causal attention, streaming softmax -----------------------
// qkv [B,T,3D]; y [B,T,D]. One thread owns one query row; K/V tiles in LDS.
// grid (T/256, H, B), block 256.
__global__ __launch_bounds__(256) void attn_kernel(const float* __restrict__ qkv,
                                                   float* __restrict__ y) {
  __shared__ __align__(16) float Ks[64][64];
  __shared__ __align__(16) float Vs[64][64];
  int b = blockIdx.z, h = blockIdx.y;
  int qrow = blockIdx.x * 256 + threadIdx.x;
  const float* base = qkv + (size_t)b * Tv * 3 * Dv;

  float q[64];
  const float* qp = base + (size_t)qrow * 3 * Dv + h * HDv;
  #pragma unroll
  for (int d4 = 0; d4 < 64; d4 += 4) {
    float4 v = *(const float4*)(qp + d4);
    q[d4 + 0] = v.x * 0.125f;   // 1/sqrt(64)
    q[d4 + 1] = v.y * 0.125f;
    q[d4 + 2] = v.z * 0.125f;
    q[d4 + 3] = v.w * 0.125f;
  }
  float o[64];
  #pragma unroll
  for (int d = 0; d < 64; ++d) o[d] = 0.f;
  float m = -1e30f, l = 0.f;

  int ntiles = (blockIdx.x + 1) * 4;  // covers k up to qbase+255
  for (int kt = 0; kt < ntiles; ++kt) {
    int kbase = kt * 64;
    __syncthreads();
    #pragma unroll
    for (int it = 0; it < 4; ++it) {
      int r  = (threadIdx.x >> 4) + it * 16;
      int c4 = (threadIdx.x & 15) * 4;
      const float* kp = base + (size_t)(kbase + r) * 3 * Dv + Dv + h * HDv + c4;
      *(float4*)&Ks[r][c4] = *(const float4*)kp;
      *(float4*)&Vs[r][c4] = *(const float4*)(kp + Dv);
    }
    __syncthreads();
    int jmax = qrow - kbase;
    if (jmax < 0) continue;
    if (jmax > 63) jmax = 63;
    for (int j = 0; j <= jmax; ++j) {
      float s = 0.f;
      #pragma unroll
      for (int d4 = 0; d4 < 64; d4 += 4) {
        float4 kv = *(const float4*)&Ks[j][d4];
        s += q[d4 + 0] * kv.x + q[d4 + 1] * kv.y + q[d4 + 2] * kv.z + q[d4 + 3] * kv.w;
      }
      float mn = fmaxf(m, s);
      float p  = __expf(s - mn);
      float sc = __expf(m - mn);
      l = l * sc + p;
      #pragma unroll
      for (int d4 = 0; d4 < 64; d4 += 4) {
        float4 vv = *(const float4*)&Vs[j][d4];
        o[d4 + 0] = o[d4 + 0] * sc + p * vv.x;
        o[d4 + 1] = o[d4 + 1] * sc + p * vv.y;
        o[d4 + 2] = o[d4 + 2] * sc + p * vv.z;
        o[d4 + 3] = o[d4 + 3] * sc + p * vv.w;
      }
      m = mn;
    }
  }
  float inv = 1.f / l;
  float* yp = y + ((size_t)(b * Tv + qrow)) * Dv + h * HDv;
  #pragma unroll
  for (int d4 = 0; d4 < 64; d4 += 4) {
    float4 o4 = make_float4(o[d4] * inv, o[d4 + 1] * inv, o[d4 + 2] * inv, o[d4 + 3] * inv);
    *(float4*)(yp + d4) = o4;
  }
}

extern "C" void kernel_launch(void* const* d_in, const int* in_sizes, int n_in,
                              void* d_out, int out_size, void* d_ws, size_t ws_size,
                              hipStream_t stream) {
  const int*   idx      = (const int*)  d_in[0];
  const float* wte      = (const float*)d_in[1];
  const float* wpe      = (const float*)d_in[2];
  const float* ln1_w    = (const float*)d_in[3];
  const float* ln1_b    = (const float*)d_in[4];
  const float* attn_w   = (const float*)d_in[5];
  const float* attn_b   = (const float*)d_in[6];
  const float* proj_w   = (const float*)d_in[7];
  const float* proj_b   = (const float*)d_in[8];
  const float* ln2_w    = (const float*)d_in[9];
  const float* ln2_b    = (const float*)d_in[10];
  const float* fc_w     = (const float*)d_in[11];
  const float* fc_b     = (const float*)d_in[12];
  const float* fcproj_w = (const float*)d_in[13];
  const float* fcproj_b = (const float*)d_in[14];
  const float* lnf_w    = (const float*)d_in[15];
  const float* lnf_b    = (const float*)d_in[16];
  const float* head_w   = (const float*)d_in[17];
  float* outp = (float*)d_out;

  float* ws   = (float*)d_ws;
  float* x    = ws;                          // [2048,768]
  float* h    = x + (size_t)MROWS * Dv;      // [2048,768]
  float* qkv  = h + (size_t)MROWS * Dv;      // [2048,2304]
  float* y    = qkv + (size_t)MROWS * 3 * Dv;// [2048,768]
  float* m4   = qkv;                         // [2048,3072] aliases dead qkv+y

  embed_kernel<<<(MROWS * Dv / 4 + 255) / 256, 256, 0, stream>>>(idx, wte, wpe, x);

  for (int l = 0; l < Lv; ++l) {
    ln_kernel<<<MROWS, 256, 0, stream>>>(x, ln1_w + (size_t)l * Dv, ln1_b + (size_t)l * Dv, h);
    gemm_kernel<0><<<dim3(3 * Dv / 64, MROWS / 64), 256, 0, stream>>>(
        h, attn_w + (size_t)l * Dv * 3 * Dv, attn_b + (size_t)l * 3 * Dv,
        nullptr, qkv, MROWS, 3 * Dv, Dv);
    attn_kernel<<<dim3(Tv / 256, Hv, Bv), 256, 0, stream>>>(qkv, y);
    gemm_kernel<0><<<dim3(Dv / 64, MROWS / 64), 256, 0, stream>>>(
        y, proj_w + (size_t)l * Dv * Dv, proj_b + (size_t)l * Dv,
        x, x, MROWS, Dv, Dv);
    ln_kernel<<<MROWS, 256, 0, stream>>>(x, ln2_w + (size_t)l * Dv, ln2_b + (size_t)l * Dv, h);
    gemm_kernel<1><<<dim3(4 * Dv / 64, MROWS / 64), 256, 0, stream>>>(
        h, fc_w + (size_t)l * Dv * 4 * Dv, fc_b + (size_t)l * 4 * Dv,
        nullptr, m4, MROWS, 4 * Dv, Dv);
    gemm_kernel<0><<<dim3(Dv / 64, MROWS / 64), 256, 0, stream>>>(
        m4, fcproj_w + (size_t)l * 4 * Dv * Dv, fcproj_b + (size_t)l * Dv,
        x, x, MROWS, Dv, 4 * Dv);
  }

  ln_kernel<<<MROWS, 256, 0, stream>>>(x, lnf_w, lnf_b, h);
  gemm_kernel<0><<<dim3(Vv / 64, MROWS / 64), 256, 0, stream>>>(
      h, head_w, nullptr, nullptr, outp, MROWS, Vv, Dv);
}

// Round 2
// 3426.530 us; speedup vs baseline: 2.2303x; 2.2303x over previous
//
#include <hip/hip_runtime.h>
#include <hip/hip_bf16.h>
#include <math.h>

static constexpr int Bv = 2, Tv = 1024, Dv = 768, Hv = 12, Lv = 6, Vv = 32000, HDv = 64;
static constexpr int MROWS = Bv * Tv;   // 2048

typedef __attribute__((ext_vector_type(8))) short bf16x8;
typedef __attribute__((ext_vector_type(4))) float f32x4;

typedef __attribute__((address_space(1))) const void gvoid;
typedef __attribute__((address_space(3))) void svoid;
__device__ __forceinline__ void gld16(const void* g, void* s) {
  __builtin_amdgcn_global_load_lds((gvoid*)g, (svoid*)s, 16, 0, 0);
}

// ---------------- embedding ----------------
__global__ __launch_bounds__(256) void embed_kernel(const int* __restrict__ idx,
                                                    const float* __restrict__ wte,
                                                    const float* __restrict__ wpe,
                                                    float* __restrict__ x) {
  int i4 = blockIdx.x * 256 + threadIdx.x;
  int total = MROWS * Dv / 4;
  if (i4 >= total) return;
  int d4 = (i4 % (Dv / 4)) * 4;
  int bt = i4 / (Dv / 4);
  int t  = bt % Tv;
  int id = idx[bt];
  float4 a = *(const float4*)(wte + (size_t)id * Dv + d4);
  float4 p = *(const float4*)(wpe + (size_t)t  * Dv + d4);
  a.x += p.x; a.y += p.y; a.z += p.z; a.w += p.w;
  *(float4*)(x + (size_t)bt * Dv + d4) = a;
}

// ---------------- layernorm: fp32 in -> bf16 out ----------------
__global__ __launch_bounds__(256) void ln_kernel(const float* __restrict__ x,
                                                 const float* __restrict__ w,
                                                 const float* __restrict__ b,
                                                 __hip_bfloat16* __restrict__ out) {
  int row = blockIdx.x;
  const float* xr = x + (size_t)row * Dv;
  int tid = threadIdx.x;
  float v0 = xr[tid], v1 = xr[tid + 256], v2 = xr[tid + 512];
  __shared__ float red[8];
  int wid = tid >> 6, lane = tid & 63;

  float s = v0 + v1 + v2;
  #pragma unroll
  for (int off = 1; off < 64; off <<= 1) s += __shfl_xor(s, off, 64);
  if (lane == 0) red[wid] = s;
  __syncthreads();
  s = red[0] + red[1] + red[2] + red[3];
  float mu = s * (1.0f / Dv);

  float d0 = v0 - mu, d1 = v1 - mu, d2 = v2 - mu;
  float q = d0 * d0 + d1 * d1 + d2 * d2;
  #pragma unroll
  for (int off = 1; off < 64; off <<= 1) q += __shfl_xor(q, off, 64);
  if (lane == 0) red[4 + wid] = q;
  __syncthreads();
  q = red[4] + red[5] + red[6] + red[7];
  float rs = rsqrtf(q * (1.0f / Dv) + 1e-5f);

  __hip_bfloat16* orow = out + (size_t)row * Dv;
  orow[tid]       = __float2bfloat16(d0 * rs * w[tid]       + b[tid]);
  orow[tid + 256] = __float2bfloat16(d1 * rs * w[tid + 256] + b[tid + 256]);
  orow[tid + 512] = __float2bfloat16(d2 * rs * w[tid + 512] + b[tid + 512]);
}

// ---------------- transpose + cast: W[K,N] f32 -> Wt[N,K] bf16 ----------------
__global__ __launch_bounds__(256) void tcast_kernel(const float* __restrict__ W,
                                                    __hip_bfloat16* __restrict__ Wt,
                                                    int K, int N) {
  __shared__ float tile[32][33];
  int n0 = blockIdx.x * 32, k0 = blockIdx.y * 32;
  int tx = threadIdx.x & 31, ty = threadIdx.x >> 5;   // ty 0..7
  #pragma unroll
  for (int r = 0; r < 32; r += 8)
    tile[ty + r][tx] = W[(size_t)(k0 + ty + r) * N + n0 + tx];
  __syncthreads();
  #pragma unroll
  for (int r = 0; r < 32; r += 8)
    Wt[(size_t)(n0 + ty + r) * K + k0 + tx] = __float2bfloat16(tile[tx][ty + r]);
}

// ---------------- bf16 MFMA GEMM: out = act(A@W^T + bias) (+resid) ----------------
// A [M,K] bf16 row-major, Wt [N,K] bf16 row-major. 128x128 tile, BK=32,
// 256 thr = 4 waves (2x2), each wave 64x64 via 4x4 frags of 16x16x32.
template <bool GELU, bool OBF>
__global__ __launch_bounds__(256) void gemm_kernel(const __hip_bfloat16* __restrict__ A,
                                                   const __hip_bfloat16* __restrict__ Wt,
                                                   const float* __restrict__ bias,
                                                   const float* __restrict__ resid,
                                                   void* __restrict__ outv,
                                                   int M, int N, int K) {
  __shared__ short As[128 * 32];
  __shared__ short Bs[128 * 32];
  int tid = threadIdx.x;
  int w = tid >> 6, lane = tid & 63;
  int wr = w >> 1, wc = w & 1;
  int m0 = blockIdx.y * 128, n0 = blockIdx.x * 128;

  f32x4 acc[4][4];
  #pragma unroll
  for (int m = 0; m < 4; ++m)
    #pragma unroll
    for (int n = 0; n < 4; ++n) acc[m][n] = (f32x4){0.f, 0.f, 0.f, 0.f};

  int lr = lane & 15, lk = lane >> 4;
  const short* abase = As + (wr * 64 + lr) * 32 + lk * 8;
  const short* bbase = Bs + (wc * 64 + lr) * 32 + lk * 8;
  int ko = (lane & 3) * 8;         // k element offset for staging
  int rsub = lane >> 2;            // 0..15 row within chunk

  for (int k0 = 0; k0 < K; k0 += 32) {
    __syncthreads();
    #pragma unroll
    for (int e = 0; e < 2; ++e) {
      int chunk = e * 4 + w;                 // 0..7
      int row = chunk * 16 + rsub;           // 0..127
      gld16(A  + (size_t)(m0 + row) * K + k0 + ko, As + chunk * 512);
      gld16(Wt + (size_t)(n0 + row) * K + k0 + ko, Bs + chunk * 512);
    }
    __syncthreads();
    bf16x8 af[4], bf[4];
    #pragma unroll
    for (int m = 0; m < 4; ++m) af[m] = *(const bf16x8*)(abase + m * 512);
    #pragma unroll
    for (int n = 0; n < 4; ++n) bf[n] = *(const bf16x8*)(bbase + n * 512);
    #pragma unroll
    for (int m = 0; m < 4; ++m)
      #pragma unroll
      for (int n = 0; n < 4; ++n)
        acc[m][n] = __builtin_amdgcn_mfma_f32_16x16x32_bf16(af[m], bf[n], acc[m][n], 0, 0, 0);
  }

  int row0 = m0 + wr * 64, col0 = n0 + wc * 64;
  float* outf = (float*)outv;
  __hip_bfloat16* outb = (__hip_bfloat16*)outv;
  #pragma unroll
  for (int n = 0; n < 4; ++n) {
    int col = col0 + n * 16 + lr;
    float bv = bias ? bias[col] : 0.f;
    #pragma unroll
    for (int m = 0; m < 4; ++m) {
      int rbase = row0 + m * 16 + lk * 4;
      #pragma unroll
      for (int j = 0; j < 4; ++j) {
        float v = acc[m][n][j] + bv;
        if (GELU) v = 0.5f * v * (1.0f + erff(v * 0.70710678118f));
        size_t o = (size_t)(rbase + j) * N + col;
        if (resid) v += resid[o];
        if (OBF) outb[o] = __float2bfloat16(v);
        else     outf[o] = v;
      }
    }
  }
}

// ---------------- causal attention, 8 lanes per query row ----------------
// qkv [B,T,3D] f32; y [B,T,D] bf16. grid (T/32, H, B), block 256.
typedef __attribute__((ext_vector_type(8))) short short8;
__global__ __launch_bounds__(256) void attn_kernel(const float* __restrict__ qkv,
                                                   __hip_bfloat16* __restrict__ y) {
  __shared__ __align__(16) float Ks[64][64];
  __shared__ __align__(16) float Vs[64][64];
  int b = blockIdx.z, h = blockIdx.y;
  int qb = blockIdx.x * 32;
  int tid = threadIdx.x;
  int g = tid >> 3, e = tid & 7;          // row group 0..31, lane-in-group 0..7
  int qrow = qb + g;
  const float* base = qkv + (size_t)b * Tv * 3 * Dv;

  float q[8];
  const float* qp = base + (size_t)qrow * 3 * Dv + h * HDv + e * 8;
  #pragma unroll
  for (int c = 0; c < 8; c += 4) {
    float4 v = *(const float4*)(qp + c);
    q[c + 0] = v.x * 0.125f; q[c + 1] = v.y * 0.125f;
    q[c + 2] = v.z * 0.125f; q[c + 3] = v.w * 0.125f;
  }
  float o[8] = {0.f, 0.f, 0.f, 0.f, 0.f, 0.f, 0.f, 0.f};
  float m = -1e30f, l = 0.f;

  int ntiles = (qb >> 6) + 1;
  for (int kt = 0; kt < ntiles; ++kt) {
    int kbase = kt * 64;
    __syncthreads();
    #pragma unroll
    for (int it = 0; it < 4; ++it) {
      int idx = it * 256 + tid;
      int r = idx >> 4, c4 = (idx & 15) * 4;
      const float* kp = base + (size_t)(kbase + r) * 3 * Dv + Dv + h * HDv + c4;
      *(float4*)&Ks[r][c4] = *(const float4*)kp;
      *(float4*)&Vs[r][c4] = *(const float4*)(kp + Dv);
    }
    __syncthreads();
    int jlimit = qb + 31 - kbase; if (jlimit > 63) jlimit = 63;
    int jmine = qrow - kbase;
    for (int j = 0; j <= jlimit; ++j) {
      if (j <= jmine) {
        float s = 0.f;
        #pragma unroll
        for (int i = 0; i < 8; ++i) s += q[i] * Ks[j][e * 8 + i];
        s += __shfl_xor(s, 1, 64);
        s += __shfl_xor(s, 2, 64);
        s += __shfl_xor(s, 4, 64);
        float mn = fmaxf(m, s);
        float p  = __expf(s - mn);
        float sc = __expf(m - mn);
        l = l * sc + p;
        #pragma unroll
        for (int i = 0; i < 8; ++i) o[i] = o[i] * sc + p * Vs[j][e * 8 + i];
        m = mn;
      }
    }
  }
  float inv = 1.f / l;
  union { short8 v; unsigned short u[8]; } pk;
  #pragma unroll
  for (int i = 0; i < 8; ++i) {
    __hip_bfloat16 hb = __float2bfloat16(o[i] * inv);
    pk.u[i] = *(unsigned short*)&hb;
  }
  *(short8*)(y + ((size_t)(b * Tv + qrow)) * Dv + h * HDv + e * 8) = pk.v;
}

extern "C" void kernel_launch(void* const* d_in, const int* in_sizes, int n_in,
                              void* d_out, int out_size, void* d_ws, size_t ws_size,
                              hipStream_t stream) {
  const int*   idx      = (const int*)  d_in[0];
  const float* wte      = (const float*)d_in[1];
  const float* wpe      = (const float*)d_in[2];
  const float* ln1_w    = (const float*)d_in[3];
  const float* ln1_b    = (const float*)d_in[4];
  const float* attn_w   = (const float*)d_in[5];
  const float* attn_b   = (const float*)d_in[6];
  const float* proj_w   = (const float*)d_in[7];
  const float* proj_b   = (const float*)d_in[8];
  const float* ln2_w    = (const float*)d_in[9];
  const float* ln2_b    = (const float*)d_in[10];
  const float* fc_w     = (const float*)d_in[11];
  const float* fc_b     = (const float*)d_in[12];
  const float* fcproj_w = (const float*)d_in[13];
  const float* fcproj_b = (const float*)d_in[14];
  const float* lnf_w    = (const float*)d_in[15];
  const float* lnf_b    = (const float*)d_in[16];
  const float* head_w   = (const float*)d_in[17];
  float* outp = (float*)d_out;

  char* w8 = (char*)d_ws;
  float*          x    = (float*)w8;                              // 2048*768 f32
  __hip_bfloat16* h    = (__hip_bfloat16*)(w8 + 6291456);         // 2048*768 bf16
  float*          qkv  = (float*)(w8 + 9437184);                  // 2048*2304 f32
  __hip_bfloat16* m4   = (__hip_bfloat16*)qkv;                    // 2048*3072 bf16 (alias)
  __hip_bfloat16* y    = (__hip_bfloat16*)(w8 + 28311552);        // 2048*768 bf16
  __hip_bfloat16* wbuf = (__hip_bfloat16*)(w8 + 31457280);        // up to 32000*768 bf16

  embed_kernel<<<(MROWS * Dv / 4 + 255) / 256, 256, 0, stream>>>(idx, wte, wpe, x);

  for (int l = 0; l < Lv; ++l) {
    ln_kernel<<<MROWS, 256, 0, stream>>>(x, ln1_w + (size_t)l * Dv, ln1_b + (size_t)l * Dv, h);

    tcast_kernel<<<dim3(3 * Dv / 32, Dv / 32), 256, 0, stream>>>(
        attn_w + (size_t)l * Dv * 3 * Dv, wbuf, Dv, 3 * Dv);
    gemm_kernel<false, false><<<dim3(3 * Dv / 128, MROWS / 128), 256, 0, stream>>>(
        h, wbuf, attn_b + (size_t)l * 3 * Dv, nullptr, qkv, MROWS, 3 * Dv, Dv);

    attn_kernel<<<dim3(Tv / 32, Hv, Bv), 256, 0, stream>>>(qkv, y);

    tcast_kernel<<<dim3(Dv / 32, Dv / 32), 256, 0, stream>>>(
        proj_w + (size_t)l * Dv * Dv, wbuf, Dv, Dv);
    gemm_kernel<false, false><<<dim3(Dv / 128, MROWS / 128), 256, 0, stream>>>(
        y, wbuf, proj_b + (size_t)l * Dv, x, x, MROWS, Dv, Dv);

    ln_kernel<<<MROWS, 256, 0, stream>>>(x, ln2_w + (size_t)l * Dv, ln2_b + (size_t)l * Dv, h);

    tcast_kernel<<<dim3(4 * Dv / 32, Dv / 32), 256, 0, stream>>>(
        fc_w + (size_t)l * Dv * 4 * Dv, wbuf, Dv, 4 * Dv);
    gemm_kernel<true, true><<<dim3(4 * Dv / 128, MROWS / 128), 256, 0, stream>>>(
        h, wbuf, fc_b + (size_t)l * 4 * Dv, nullptr, m4, MROWS, 4 * Dv, Dv);

    tcast_kernel<<<dim3(Dv / 32, 4 * Dv / 32), 256, 0, stream>>>(
        fcproj_w + (size_t)l * 4 * Dv * Dv, wbuf, 4 * Dv, Dv);
    gemm_kernel<false, false><<<dim3(Dv / 128, MROWS / 128), 256, 0, stream>>>(
        m4, wbuf, fcproj_b + (size_t)l * Dv, x, x, MROWS, Dv, 4 * Dv);
  }

  ln_kernel<<<MROWS, 256, 0, stream>>>(x, lnf_w, lnf_b, h);
  tcast_kernel<<<dim3(Vv / 32, Dv / 32), 256, 0, stream>>>(head_w, wbuf, Dv, Vv);
  gemm_kernel<false, false><<<dim3(Vv / 128, MROWS / 128), 256, 0, stream>>>(
      h, wbuf, nullptr, nullptr, outp, MROWS, Vv, Dv);
}

// Round 3
// 1617.239 us; speedup vs baseline: 4.7255x; 2.1188x over previous
//
#include <hip/hip_runtime.h>
#include <hip/hip_bf16.h>
#include <math.h>

static constexpr int Bv = 2, Tv = 1024, Dv = 768, Hv = 12, Lv = 6, Vv = 32000, HDv = 64;
static constexpr int MROWS = Bv * Tv;   // 2048

typedef __attribute__((ext_vector_type(8))) short bf16x8;
typedef __attribute__((ext_vector_type(8))) short short8;
typedef __attribute__((ext_vector_type(4))) float f32x4;

typedef __attribute__((address_space(1))) const void gvoid;
typedef __attribute__((address_space(3))) void svoid;
__device__ __forceinline__ void gld16(const void* g, void* s) {
  __builtin_amdgcn_global_load_lds((gvoid*)g, (svoid*)s, 16, 0, 0);
}
__device__ __forceinline__ short f2bf(float v) {
  __hip_bfloat16 hb = __float2bfloat16(v);
  return *reinterpret_cast<short*>(&hb);
}

// ---------------- embedding ----------------
__global__ __launch_bounds__(256) void embed_kernel(const int* __restrict__ idx,
                                                    const float* __restrict__ wte,
                                                    const float* __restrict__ wpe,
                                                    float* __restrict__ x) {
  int i4 = blockIdx.x * 256 + threadIdx.x;
  int total = MROWS * Dv / 4;
  if (i4 >= total) return;
  int d4 = (i4 % (Dv / 4)) * 4;
  int bt = i4 / (Dv / 4);
  int t  = bt % Tv;
  int id = idx[bt];
  float4 a = *(const float4*)(wte + (size_t)id * Dv + d4);
  float4 p = *(const float4*)(wpe + (size_t)t  * Dv + d4);
  a.x += p.x; a.y += p.y; a.z += p.z; a.w += p.w;
  *(float4*)(x + (size_t)bt * Dv + d4) = a;
}

// ---------------- layernorm: fp32 in -> bf16 out ----------------
__global__ __launch_bounds__(256) void ln_kernel(const float* __restrict__ x,
                                                 const float* __restrict__ w,
                                                 const float* __restrict__ b,
                                                 __hip_bfloat16* __restrict__ out) {
  int row = blockIdx.x;
  const float* xr = x + (size_t)row * Dv;
  int tid = threadIdx.x;
  float v0 = xr[tid], v1 = xr[tid + 256], v2 = xr[tid + 512];
  __shared__ float red[8];
  int wid = tid >> 6, lane = tid & 63;

  float s = v0 + v1 + v2;
  #pragma unroll
  for (int off = 1; off < 64; off <<= 1) s += __shfl_xor(s, off, 64);
  if (lane == 0) red[wid] = s;
  __syncthreads();
  s = red[0] + red[1] + red[2] + red[3];
  float mu = s * (1.0f / Dv);

  float d0 = v0 - mu, d1 = v1 - mu, d2 = v2 - mu;
  float q = d0 * d0 + d1 * d1 + d2 * d2;
  #pragma unroll
  for (int off = 1; off < 64; off <<= 1) q += __shfl_xor(q, off, 64);
  if (lane == 0) red[4 + wid] = q;
  __syncthreads();
  q = red[4] + red[5] + red[6] + red[7];
  float rs = rsqrtf(q * (1.0f / Dv) + 1e-5f);

  __hip_bfloat16* orow = out + (size_t)row * Dv;
  orow[tid]       = __float2bfloat16(d0 * rs * w[tid]       + b[tid]);
  orow[tid + 256] = __float2bfloat16(d1 * rs * w[tid + 256] + b[tid + 256]);
  orow[tid + 512] = __float2bfloat16(d2 * rs * w[tid + 512] + b[tid + 512]);
}

// ---------------- transpose + cast: W[K,N] f32 -> Wt[N,K] bf16 ----------------
__global__ __launch_bounds__(256) void tcast_kernel(const float* __restrict__ W,
                                                    __hip_bfloat16* __restrict__ Wt,
                                                    int K, int N) {
  __shared__ float tile[32][33];
  int n0 = blockIdx.x * 32, k0 = blockIdx.y * 32;
  int tx = threadIdx.x & 31, ty = threadIdx.x >> 5;   // ty 0..7
  #pragma unroll
  for (int r = 0; r < 32; r += 8)
    tile[ty + r][tx] = W[(size_t)(k0 + ty + r) * N + n0 + tx];
  __syncthreads();
  #pragma unroll
  for (int r = 0; r < 32; r += 8)
    Wt[(size_t)(n0 + ty + r) * K + k0 + tx] = __float2bfloat16(tile[tx][ty + r]);
}

// ---------------- V transpose: qkv[b,t,2D+h*64+d] -> vt[b,h,d,t] (bf16) -----
__global__ __launch_bounds__(256) void vtr_kernel(const __hip_bfloat16* __restrict__ qkv,
                                                  __hip_bfloat16* __restrict__ vt) {
  __shared__ short tile[64][72];
  int b = blockIdx.z, h = blockIdx.y;
  int t0 = blockIdx.x * 64;
  int tid = threadIdx.x;
  int row = tid >> 2, c0 = (tid & 3) * 16;
  const __hip_bfloat16* src = qkv + ((size_t)(b * Tv + t0 + row)) * 3 * Dv + 2 * Dv + h * HDv + c0;
  *(short8*)&tile[row][c0]     = *(const short8*)src;
  *(short8*)&tile[row][c0 + 8] = *(const short8*)(src + 8);
  __syncthreads();
  int d = tid >> 2;
  union { short8 v[2]; short u[16]; } pk;
  #pragma unroll
  for (int i = 0; i < 16; ++i) pk.u[i] = tile[c0 + i][d];
  __hip_bfloat16* dst = vt + ((size_t)((b * Hv + h) * HDv + d)) * Tv + t0 + c0;
  *(short8*)dst       = pk.v[0];
  *(short8*)(dst + 8) = pk.v[1];
}

// ---------------- bf16 MFMA GEMM: out = act(A@W^T + bias) (+resid) ----------
template <bool GELU, bool OBF>
__global__ __launch_bounds__(256) void gemm_kernel(const __hip_bfloat16* __restrict__ A,
                                                   const __hip_bfloat16* __restrict__ Wt,
                                                   const float* __restrict__ bias,
                                                   const float* __restrict__ resid,
                                                   void* __restrict__ outv,
                                                   int M, int N, int K) {
  __shared__ short As[128 * 32];
  __shared__ short Bs[128 * 32];
  int tid = threadIdx.x;
  int w = tid >> 6, lane = tid & 63;
  int wr = w >> 1, wc = w & 1;
  int m0 = blockIdx.y * 128, n0 = blockIdx.x * 128;

  f32x4 acc[4][4];
  #pragma unroll
  for (int m = 0; m < 4; ++m)
    #pragma unroll
    for (int n = 0; n < 4; ++n) acc[m][n] = (f32x4){0.f, 0.f, 0.f, 0.f};

  int lr = lane & 15, lk = lane >> 4;
  const short* abase = As + (wr * 64 + lr) * 32 + lk * 8;
  const short* bbase = Bs + (wc * 64 + lr) * 32 + lk * 8;
  int ko = (lane & 3) * 8;
  int rsub = lane >> 2;

  for (int k0 = 0; k0 < K; k0 += 32) {
    __syncthreads();
    #pragma unroll
    for (int e = 0; e < 2; ++e) {
      int chunk = e * 4 + w;
      int row = chunk * 16 + rsub;
      gld16(A  + (size_t)(m0 + row) * K + k0 + ko, As + chunk * 512);
      gld16(Wt + (size_t)(n0 + row) * K + k0 + ko, Bs + chunk * 512);
    }
    __syncthreads();
    bf16x8 af[4], bf[4];
    #pragma unroll
    for (int m = 0; m < 4; ++m) af[m] = *(const bf16x8*)(abase + m * 512);
    #pragma unroll
    for (int n = 0; n < 4; ++n) bf[n] = *(const bf16x8*)(bbase + n * 512);
    #pragma unroll
    for (int m = 0; m < 4; ++m)
      #pragma unroll
      for (int n = 0; n < 4; ++n)
        acc[m][n] = __builtin_amdgcn_mfma_f32_16x16x32_bf16(af[m], bf[n], acc[m][n], 0, 0, 0);
  }

  int row0 = m0 + wr * 64, col0 = n0 + wc * 64;
  float* outf = (float*)outv;
  __hip_bfloat16* outb = (__hip_bfloat16*)outv;
  #pragma unroll
  for (int n = 0; n < 4; ++n) {
    int col = col0 + n * 16 + lr;
    float bv = bias ? bias[col] : 0.f;
    #pragma unroll
    for (int m = 0; m < 4; ++m) {
      int rbase = row0 + m * 16 + lk * 4;
      #pragma unroll
      for (int j = 0; j < 4; ++j) {
        float v = acc[m][n][j] + bv;
        if (GELU) v = 0.5f * v * (1.0f + erff(v * 0.70710678118f));
        size_t o = (size_t)(rbase + j) * N + col;
        if (resid) v += resid[o];
        if (OBF) outb[o] = __float2bfloat16(v);
        else     outf[o] = v;
      }
    }
  }
}

// ---------------- MFMA flash attention ----------------
// qkv [B,T,3D] bf16, vt [B,H,HD,T] bf16, y [B,T,D] bf16.
// grid (T/64, H, B) with qtile reversed; 256 thr = 4 waves; wave owns 16 q rows.
__global__ __launch_bounds__(256) void attn_kernel(const __hip_bfloat16* __restrict__ qkv,
                                                   const __hip_bfloat16* __restrict__ vt,
                                                   __hip_bfloat16* __restrict__ y) {
  __shared__ short Ks[64 * 64];
  __shared__ short Vts[64 * 64];
  __shared__ short Ps[4][16 * 64];
  int b = blockIdx.z, h = blockIdx.y;
  int qb = (gridDim.x - 1 - blockIdx.x) * 64;   // big tiles first
  int tid = threadIdx.x;
  int w = tid >> 6, l = tid & 63;
  int lr = l & 15, lk = l >> 4;

  // Q A-fragments (2 k-frags over d)
  bf16x8 aq[2];
  {
    const __hip_bfloat16* qp = qkv + ((size_t)(b * Tv + qb + w * 16 + lr)) * 3 * Dv + h * HDv + lk * 8;
    aq[0] = *(const bf16x8*)qp;
    aq[1] = *(const bf16x8*)(qp + 32);
  }

  f32x4 o[4];
  #pragma unroll
  for (int n = 0; n < 4; ++n) o[n] = (f32x4){0.f, 0.f, 0.f, 0.f};
  float mrow[4] = {-1e30f, -1e30f, -1e30f, -1e30f};
  float lrow[4] = {0.f, 0.f, 0.f, 0.f};

  int r8 = l >> 3, c8 = l & 7;
  int nt = qb / 64 + 1;

  for (int kt = 0; kt < nt; ++kt) {
    int kbase = kt * 64;
    __syncthreads();
    #pragma unroll
    for (int e = 0; e < 2; ++e) {
      int r0 = w * 16 + e * 8;
      int rK = r0 + r8;
      int csK = c8 ^ (rK & 7);
      gld16(qkv + ((size_t)(b * Tv + kbase + rK)) * 3 * Dv + Dv + h * HDv + csK * 8,
            Ks + r0 * 64);
      int csV = csK;   // same row parity
      gld16(vt + ((size_t)((b * Hv + h) * HDv + rK)) * Tv + kbase + csV * 8,
            Vts + r0 * 64);
    }
    __syncthreads();

    // S = Q K^T
    f32x4 s[4];
    #pragma unroll
    for (int n = 0; n < 4; ++n) s[n] = (f32x4){0.f, 0.f, 0.f, 0.f};
    #pragma unroll
    for (int kf = 0; kf < 2; ++kf)
      #pragma unroll
      for (int nf = 0; nf < 4; ++nf) {
        int row = nf * 16 + lr;
        int g = (kf * 4 + lk) ^ (row & 7);
        bf16x8 bk = *(const bf16x8*)(Ks + row * 64 + g * 8);
        s[nf] = __builtin_amdgcn_mfma_f32_16x16x32_bf16(aq[kf], bk, s[nf], 0, 0, 0);
      }
    #pragma unroll
    for (int nf = 0; nf < 4; ++nf)
      #pragma unroll
      for (int j = 0; j < 4; ++j) s[nf][j] *= 0.125f;

    if (kt == nt - 1) {   // diagonal tile: causal mask
      #pragma unroll
      for (int nf = 0; nf < 4; ++nf) {
        int kl = nf * 16 + lr;
        #pragma unroll
        for (int j = 0; j < 4; ++j)
          if (kl > w * 16 + lk * 4 + j) s[nf][j] = -1e30f;
      }
    }

    float sc[4];
    #pragma unroll
    for (int j = 0; j < 4; ++j) {
      float pm = fmaxf(fmaxf(s[0][j], s[1][j]), fmaxf(s[2][j], s[3][j]));
      pm = fmaxf(pm, __shfl_xor(pm, 1, 64));
      pm = fmaxf(pm, __shfl_xor(pm, 2, 64));
      pm = fmaxf(pm, __shfl_xor(pm, 4, 64));
      pm = fmaxf(pm, __shfl_xor(pm, 8, 64));
      float mn = fmaxf(mrow[j], pm);
      sc[j] = __expf(mrow[j] - mn);
      mrow[j] = mn;
    }
    #pragma unroll
    for (int j = 0; j < 4; ++j) {
      float ls = 0.f;
      #pragma unroll
      for (int nf = 0; nf < 4; ++nf) {
        float p = __expf(s[nf][j] - mrow[j]);
        s[nf][j] = p;
        ls += p;
      }
      ls += __shfl_xor(ls, 1, 64);
      ls += __shfl_xor(ls, 2, 64);
      ls += __shfl_xor(ls, 4, 64);
      ls += __shfl_xor(ls, 8, 64);
      lrow[j] = lrow[j] * sc[j] + ls;
    }
    #pragma unroll
    for (int n = 0; n < 4; ++n)
      #pragma unroll
      for (int j = 0; j < 4; ++j) o[n][j] *= sc[j];

    // P -> LDS (swizzled), per-wave private
    short* pw = Ps[w];
    #pragma unroll
    for (int nf = 0; nf < 4; ++nf)
      #pragma unroll
      for (int j = 0; j < 4; ++j) {
        int ql = lk * 4 + j, k = nf * 16 + lr;
        pw[ql * 64 + (((k >> 3) ^ (ql & 7)) * 8) + (k & 7)] = f2bf(s[nf][j]);
      }
    bf16x8 pa[2];
    #pragma unroll
    for (int kf = 0; kf < 2; ++kf) {
      int g = (kf * 4 + lk) ^ (lr & 7);
      pa[kf] = *(const bf16x8*)(pw + lr * 64 + g * 8);
    }
    #pragma unroll
    for (int kf = 0; kf < 2; ++kf)
      #pragma unroll
      for (int nf = 0; nf < 4; ++nf) {
        int d = nf * 16 + lr;
        int g = (kf * 4 + lk) ^ (d & 7);
        bf16x8 bv = *(const bf16x8*)(Vts + d * 64 + g * 8);
        o[nf] = __builtin_amdgcn_mfma_f32_16x16x32_bf16(pa[kf], bv, o[nf], 0, 0, 0);
      }
  }

  #pragma unroll
  for (int j = 0; j < 4; ++j) lrow[j] = 1.f / lrow[j];
  #pragma unroll
  for (int nf = 0; nf < 4; ++nf)
    #pragma unroll
    for (int j = 0; j < 4; ++j) {
      size_t oidx = ((size_t)(b * Tv + qb + w * 16 + lk * 4 + j)) * Dv + h * HDv + nf * 16 + lr;
      y[oidx] = __float2bfloat16(o[nf][j] * lrow[j]);
    }
}

extern "C" void kernel_launch(void* const* d_in, const int* in_sizes, int n_in,
                              void* d_out, int out_size, void* d_ws, size_t ws_size,
                              hipStream_t stream) {
  const int*   idx      = (const int*)  d_in[0];
  const float* wte      = (const float*)d_in[1];
  const float* wpe      = (const float*)d_in[2];
  const float* ln1_w    = (const float*)d_in[3];
  const float* ln1_b    = (const float*)d_in[4];
  const float* attn_w   = (const float*)d_in[5];
  const float* attn_b   = (const float*)d_in[6];
  const float* proj_w   = (const float*)d_in[7];
  const float* proj_b   = (const float*)d_in[8];
  const float* ln2_w    = (const float*)d_in[9];
  const float* ln2_b    = (const float*)d_in[10];
  const float* fc_w     = (const float*)d_in[11];
  const float* fc_b     = (const float*)d_in[12];
  const float* fcproj_w = (const float*)d_in[13];
  const float* fcproj_b = (const float*)d_in[14];
  const float* lnf_w    = (const float*)d_in[15];
  const float* lnf_b    = (const float*)d_in[16];
  const float* head_w   = (const float*)d_in[17];
  float* outp = (float*)d_out;

  char* w8 = (char*)d_ws;
  float*          x    = (float*)w8;                          // 2048*768 f32
  __hip_bfloat16* h    = (__hip_bfloat16*)(w8 + 6291456);     // 2048*768 bf16
  __hip_bfloat16* qkv  = (__hip_bfloat16*)(w8 + 9437184);     // 2048*2304 bf16
  __hip_bfloat16* m4   = qkv;                                 // 2048*3072 bf16 alias
  __hip_bfloat16* y    = (__hip_bfloat16*)(w8 + 22020096);    // 2048*768 bf16
  __hip_bfloat16* vt   = (__hip_bfloat16*)(w8 + 25165824);    // B*H*64*1024 bf16
  __hip_bfloat16* wbuf = (__hip_bfloat16*)(w8 + 28311552);    // up to 32000*768 bf16

  embed_kernel<<<(MROWS * Dv / 4 + 255) / 256, 256, 0, stream>>>(idx, wte, wpe, x);

  for (int l = 0; l < Lv; ++l) {
    ln_kernel<<<MROWS, 256, 0, stream>>>(x, ln1_w + (size_t)l * Dv, ln1_b + (size_t)l * Dv, h);

    tcast_kernel<<<dim3(3 * Dv / 32, Dv / 32), 256, 0, stream>>>(
        attn_w + (size_t)l * Dv * 3 * Dv, wbuf, Dv, 3 * Dv);
    gemm_kernel<false, true><<<dim3(3 * Dv / 128, MROWS / 128), 256, 0, stream>>>(
        h, wbuf, attn_b + (size_t)l * 3 * Dv, nullptr, qkv, MROWS, 3 * Dv, Dv);

    vtr_kernel<<<dim3(Tv / 64, Hv, Bv), 256, 0, stream>>>(qkv, vt);
    attn_kernel<<<dim3(Tv / 64, Hv, Bv), 256, 0, stream>>>(qkv, vt, y);

    tcast_kernel<<<dim3(Dv / 32, Dv / 32), 256, 0, stream>>>(
        proj_w + (size_t)l * Dv * Dv, wbuf, Dv, Dv);
    gemm_kernel<false, false><<<dim3(Dv / 128, MROWS / 128), 256, 0, stream>>>(
        y, wbuf, proj_b + (size_t)l * Dv, x, x, MROWS, Dv, Dv);

    ln_kernel<<<MROWS, 256, 0, stream>>>(x, ln2_w + (size_t)l * Dv, ln2_b + (size_t)l * Dv, h);

    tcast_kernel<<<dim3(4 * Dv / 32, Dv / 32), 256, 0, stream>>>(
        fc_w + (size_t)l * Dv * 4 * Dv, wbuf, Dv, 4 * Dv);
    gemm_kernel<true, true><<<dim3(4 * Dv / 128, MROWS / 128), 256, 0, stream>>>(
        h, wbuf, fc_b + (size_t)l * 4 * Dv, nullptr, m4, MROWS, 4 * Dv, Dv);

    tcast_kernel<<<dim3(Dv / 32, 4 * Dv / 32), 256, 0, stream>>>(
        fcproj_w + (size_t)l * 4 * Dv * Dv, wbuf, 4 * Dv, Dv);
    gemm_kernel<false, false><<<dim3(Dv / 128, MROWS / 128), 256, 0, stream>>>(
        m4, wbuf, fcproj_b + (size_t)l * Dv, x, x, MROWS, Dv, 4 * Dv);
  }

  ln_kernel<<<MROWS, 256, 0, stream>>>(x, lnf_w, lnf_b, h);
  tcast_kernel<<<dim3(Vv / 32, Dv / 32), 256, 0, stream>>>(head_w, wbuf, Dv, Vv);
  gemm_kernel<false, false><<<dim3(Vv / 128, MROWS / 128), 256, 0, stream>>>(
      h, wbuf, nullptr, nullptr, outp, MROWS, Vv, Dv);
}

// Round 4
// 1199.445 us; speedup vs baseline: 6.3714x; 1.3483x over previous
//
#include <hip/hip_runtime.h>
#include <hip/hip_bf16.h>
#include <math.h>

static constexpr int Bv = 2, Tv = 1024, Dv = 768, Hv = 12, Lv = 6, Vv = 32000, HDv = 64;
static constexpr int MROWS = Bv * Tv;   // 2048

typedef __attribute__((ext_vector_type(8))) short bf16x8;
typedef __attribute__((ext_vector_type(8))) short short8;
typedef __attribute__((ext_vector_type(4))) float f32x4;

typedef __attribute__((address_space(1))) const void gvoid;
typedef __attribute__((address_space(3))) void svoid;
__device__ __forceinline__ void gld16(const void* g, void* s) {
  __builtin_amdgcn_global_load_lds((gvoid*)g, (svoid*)s, 16, 0, 0);
}
__device__ __forceinline__ short f2bf(float v) {
  __hip_bfloat16 hb = __float2bfloat16(v);
  return *reinterpret_cast<short*>(&hb);
}
// bijective XCD-chunk remap (m204): consecutive wgid land on the same XCD
__device__ __forceinline__ int xcd_remap(int lin, int nwg) {
  int q = nwg >> 3, r = nwg & 7;
  int xcd = lin & 7, idx = lin >> 3;
  return (xcd < r ? xcd * (q + 1) : r * (q + 1) + (xcd - r) * q) + idx;
}

// ---------------- embedding ----------------
__global__ __launch_bounds__(256) void embed_kernel(const int* __restrict__ idx,
                                                    const float* __restrict__ wte,
                                                    const float* __restrict__ wpe,
                                                    float* __restrict__ x) {
  int i4 = blockIdx.x * 256 + threadIdx.x;
  int total = MROWS * Dv / 4;
  if (i4 >= total) return;
  int d4 = (i4 % (Dv / 4)) * 4;
  int bt = i4 / (Dv / 4);
  int t  = bt % Tv;
  int id = idx[bt];
  float4 a = *(const float4*)(wte + (size_t)id * Dv + d4);
  float4 p = *(const float4*)(wpe + (size_t)t  * Dv + d4);
  a.x += p.x; a.y += p.y; a.z += p.z; a.w += p.w;
  *(float4*)(x + (size_t)bt * Dv + d4) = a;
}

// ---------------- layernorm: fp32 in -> bf16 out ----------------
__global__ __launch_bounds__(256) void ln_kernel(const float* __restrict__ x,
                                                 const float* __restrict__ w,
                                                 const float* __restrict__ b,
                                                 __hip_bfloat16* __restrict__ out) {
  int row = blockIdx.x;
  const float* xr = x + (size_t)row * Dv;
  int tid = threadIdx.x;
  float v0 = xr[tid], v1 = xr[tid + 256], v2 = xr[tid + 512];
  __shared__ float red[8];
  int wid = tid >> 6, lane = tid & 63;

  float s = v0 + v1 + v2;
  #pragma unroll
  for (int off = 1; off < 64; off <<= 1) s += __shfl_xor(s, off, 64);
  if (lane == 0) red[wid] = s;
  __syncthreads();
  s = red[0] + red[1] + red[2] + red[3];
  float mu = s * (1.0f / Dv);

  float d0 = v0 - mu, d1 = v1 - mu, d2 = v2 - mu;
  float q = d0 * d0 + d1 * d1 + d2 * d2;
  #pragma unroll
  for (int off = 1; off < 64; off <<= 1) q += __shfl_xor(q, off, 64);
  if (lane == 0) red[4 + wid] = q;
  __syncthreads();
  q = red[4] + red[5] + red[6] + red[7];
  float rs = rsqrtf(q * (1.0f / Dv) + 1e-5f);

  __hip_bfloat16* orow = out + (size_t)row * Dv;
  orow[tid]       = __float2bfloat16(d0 * rs * w[tid]       + b[tid]);
  orow[tid + 256] = __float2bfloat16(d1 * rs * w[tid + 256] + b[tid + 256]);
  orow[tid + 512] = __float2bfloat16(d2 * rs * w[tid + 512] + b[tid + 512]);
}

// ---------------- transpose+cast body ----------------
__device__ __forceinline__ void tcast_body(const float* __restrict__ W,
                                           __hip_bfloat16* __restrict__ Wt,
                                           int K, int N, int k0, int n0) {
  __shared__ float tile[32][33];
  int tx = threadIdx.x & 31, ty = threadIdx.x >> 5;   // ty 0..7
  #pragma unroll
  for (int r = 0; r < 32; r += 8)
    tile[ty + r][tx] = W[(size_t)(k0 + ty + r) * N + n0 + tx];
  __syncthreads();
  #pragma unroll
  for (int r = 0; r < 32; r += 8)
    Wt[(size_t)(n0 + ty + r) * K + k0 + tx] = __float2bfloat16(tile[tx][ty + r]);
}

__global__ __launch_bounds__(256) void tcast_kernel(const float* __restrict__ W,
                                                    __hip_bfloat16* __restrict__ Wt,
                                                    int K, int N) {
  tcast_body(W, Wt, K, N, blockIdx.y * 32, blockIdx.x * 32);
}

// all 4 per-layer weights in one dispatch: tiles 1728 + 576 + 2304 + 2304 = 6912
__global__ __launch_bounds__(256) void tcast4_kernel(const float* __restrict__ s0,
                                                     const float* __restrict__ s1,
                                                     const float* __restrict__ s2,
                                                     const float* __restrict__ s3,
                                                     __hip_bfloat16* __restrict__ d0,
                                                     __hip_bfloat16* __restrict__ d1,
                                                     __hip_bfloat16* __restrict__ d2,
                                                     __hip_bfloat16* __restrict__ d3) {
  int lin = blockIdx.x;
  const float* W; __hip_bfloat16* Wt; int K, N, loc;
  if (lin < 1728)      { W = s0; Wt = d0; K = 768;  N = 2304; loc = lin; }
  else if (lin < 2304) { W = s1; Wt = d1; K = 768;  N = 768;  loc = lin - 1728; }
  else if (lin < 4608) { W = s2; Wt = d2; K = 768;  N = 3072; loc = lin - 2304; }
  else                 { W = s3; Wt = d3; K = 3072; N = 768;  loc = lin - 4608; }
  int nb = N / 32;
  tcast_body(W, Wt, K, N, (loc / nb) * 32, (loc % nb) * 32);
}

// ---------------- V transpose: qkv[b,t,2D+h*64+d] -> vt[b,h,d,t] ----------
__global__ __launch_bounds__(256) void vtr_kernel(const __hip_bfloat16* __restrict__ qkv,
                                                  __hip_bfloat16* __restrict__ vt) {
  __shared__ short tile[64][72];
  int b = blockIdx.z, h = blockIdx.y;
  int t0 = blockIdx.x * 64;
  int tid = threadIdx.x;
  int row = tid >> 2, c0 = (tid & 3) * 16;
  const __hip_bfloat16* src = qkv + ((size_t)(b * Tv + t0 + row)) * 3 * Dv + 2 * Dv + h * HDv + c0;
  *(short8*)&tile[row][c0]     = *(const short8*)src;
  *(short8*)&tile[row][c0 + 8] = *(const short8*)(src + 8);
  __syncthreads();
  int d = tid >> 2;
  union { short8 v[2]; short u[16]; } pk;
  #pragma unroll
  for (int i = 0; i < 16; ++i) pk.u[i] = tile[c0 + i][d];
  __hip_bfloat16* dst = vt + ((size_t)((b * Hv + h) * HDv + d)) * Tv + t0 + c0;
  *(short8*)dst       = pk.v[0];
  *(short8*)(dst + 8) = pk.v[1];
}

// ---------------- 128x128 MFMA GEMM (BK=32), M-fastest + XCD swizzle ------
// grid = dim3(M/128, N/128)
template <bool GELU, bool OBF>
__global__ __launch_bounds__(256) void gemm_kernel(const __hip_bfloat16* __restrict__ A,
                                                   const __hip_bfloat16* __restrict__ Wt,
                                                   const float* __restrict__ bias,
                                                   const float* __restrict__ resid,
                                                   void* __restrict__ outv,
                                                   int M, int N, int K) {
  __shared__ short As[128 * 32];
  __shared__ short Bs[128 * 32];
  int nwg = gridDim.x * gridDim.y;
  int wgid = xcd_remap(blockIdx.y * gridDim.x + blockIdx.x, nwg);
  int m0 = (wgid % gridDim.x) * 128, n0 = (wgid / gridDim.x) * 128;

  int tid = threadIdx.x;
  int w = tid >> 6, lane = tid & 63;
  int wr = w >> 1, wc = w & 1;

  f32x4 acc[4][4];
  #pragma unroll
  for (int m = 0; m < 4; ++m)
    #pragma unroll
    for (int n = 0; n < 4; ++n) acc[m][n] = (f32x4){0.f, 0.f, 0.f, 0.f};

  int lr = lane & 15, lk = lane >> 4;
  const short* abase = As + (wr * 64 + lr) * 32 + lk * 8;
  const short* bbase = Bs + (wc * 64 + lr) * 32 + lk * 8;
  int ko = (lane & 3) * 8;
  int rsub = lane >> 2;

  for (int k0 = 0; k0 < K; k0 += 32) {
    __syncthreads();
    #pragma unroll
    for (int e = 0; e < 2; ++e) {
      int chunk = e * 4 + w;
      int row = chunk * 16 + rsub;
      gld16(A  + (size_t)(m0 + row) * K + k0 + ko, As + chunk * 512);
      gld16(Wt + (size_t)(n0 + row) * K + k0 + ko, Bs + chunk * 512);
    }
    __syncthreads();
    bf16x8 af[4], bf[4];
    #pragma unroll
    for (int m = 0; m < 4; ++m) af[m] = *(const bf16x8*)(abase + m * 512);
    #pragma unroll
    for (int n = 0; n < 4; ++n) bf[n] = *(const bf16x8*)(bbase + n * 512);
    #pragma unroll
    for (int m = 0; m < 4; ++m)
      #pragma unroll
      for (int n = 0; n < 4; ++n)
        acc[m][n] = __builtin_amdgcn_mfma_f32_16x16x32_bf16(af[m], bf[n], acc[m][n], 0, 0, 0);
  }

  int row0 = m0 + wr * 64, col0 = n0 + wc * 64;
  float* outf = (float*)outv;
  __hip_bfloat16* outb = (__hip_bfloat16*)outv;
  #pragma unroll
  for (int n = 0; n < 4; ++n) {
    int col = col0 + n * 16 + lr;
    float bv = bias ? bias[col] : 0.f;
    #pragma unroll
    for (int m = 0; m < 4; ++m) {
      int rbase = row0 + m * 16 + lk * 4;
      #pragma unroll
      for (int j = 0; j < 4; ++j) {
        float v = acc[m][n][j] + bv;
        if (GELU) v = 0.5f * v * (1.0f + erff(v * 0.70710678118f));
        size_t o = (size_t)(rbase + j) * N + col;
        if (resid) v += resid[o];
        if (OBF) outb[o] = __float2bfloat16(v);
        else     outf[o] = v;
      }
    }
  }
}

// ---------------- 64x64 MFMA GEMM (BK=64, XOR-swizzled LDS) ----------------
// For small-N GEMMs (proj/fcproj): grid = dim3(M/64, N/64) -> full CU coverage.
__global__ __launch_bounds__(256) void gemm64_kernel(const __hip_bfloat16* __restrict__ A,
                                                     const __hip_bfloat16* __restrict__ Wt,
                                                     const float* __restrict__ bias,
                                                     const float* __restrict__ resid,
                                                     float* __restrict__ out,
                                                     int M, int N, int K) {
  __shared__ short As[64 * 64];
  __shared__ short Bs[64 * 64];
  int nwg = gridDim.x * gridDim.y;
  int wgid = xcd_remap(blockIdx.y * gridDim.x + blockIdx.x, nwg);
  int m0 = (wgid % gridDim.x) * 64, n0 = (wgid / gridDim.x) * 64;

  int tid = threadIdx.x;
  int w = tid >> 6, lane = tid & 63;
  int wr = w >> 1, wc = w & 1;

  f32x4 acc[2][2];
  #pragma unroll
  for (int m = 0; m < 2; ++m)
    #pragma unroll
    for (int n = 0; n < 2; ++n) acc[m][n] = (f32x4){0.f, 0.f, 0.f, 0.f};

  int lr = lane & 15, lk = lane >> 4;
  int rsub = lane >> 3, go = lane & 7;          // stage: row-in-8, granule

  for (int k0 = 0; k0 < K; k0 += 64) {
    __syncthreads();
    #pragma unroll
    for (int e = 0; e < 2; ++e) {
      int row = w * 16 + e * 8 + rsub;
      int gs = (go ^ rsub) * 8;                 // swizzled source granule
      gld16(A  + (size_t)(m0 + row) * K + k0 + gs, As + w * 1024 + e * 512);
      gld16(Wt + (size_t)(n0 + row) * K + k0 + gs, Bs + w * 1024 + e * 512);
    }
    __syncthreads();
    #pragma unroll
    for (int kf = 0; kf < 2; ++kf) {
      bf16x8 af[2], bf[2];
      #pragma unroll
      for (int m = 0; m < 2; ++m) {
        int row = wr * 32 + m * 16 + lr;
        af[m] = *(const bf16x8*)(As + row * 64 + (((kf * 4 + lk) ^ (row & 7)) * 8));
      }
      #pragma unroll
      for (int n = 0; n < 2; ++n) {
        int row = wc * 32 + n * 16 + lr;
        bf[n] = *(const bf16x8*)(Bs + row * 64 + (((kf * 4 + lk) ^ (row & 7)) * 8));
      }
      #pragma unroll
      for (int m = 0; m < 2; ++m)
        #pragma unroll
        for (int n = 0; n < 2; ++n)
          acc[m][n] = __builtin_amdgcn_mfma_f32_16x16x32_bf16(af[m], bf[n], acc[m][n], 0, 0, 0);
    }
  }

  int row0 = m0 + wr * 32, col0 = n0 + wc * 32;
  #pragma unroll
  for (int n = 0; n < 2; ++n) {
    int col = col0 + n * 16 + lr;
    float bv = bias ? bias[col] : 0.f;
    #pragma unroll
    for (int m = 0; m < 2; ++m) {
      int rbase = row0 + m * 16 + lk * 4;
      #pragma unroll
      for (int j = 0; j < 4; ++j) {
        float v = acc[m][n][j] + bv;
        size_t o = (size_t)(rbase + j) * N + col;
        if (resid) v += resid[o];
        out[o] = v;
      }
    }
  }
}

// ---------------- MFMA flash attention ----------------
__global__ __launch_bounds__(256) void attn_kernel(const __hip_bfloat16* __restrict__ qkv,
                                                   const __hip_bfloat16* __restrict__ vt,
                                                   __hip_bfloat16* __restrict__ y) {
  __shared__ short Ks[64 * 64];
  __shared__ short Vts[64 * 64];
  __shared__ short Ps[4][16 * 64];
  int b = blockIdx.z, h = blockIdx.y;
  int qb = (gridDim.x - 1 - blockIdx.x) * 64;   // big tiles first
  int tid = threadIdx.x;
  int w = tid >> 6, l = tid & 63;
  int lr = l & 15, lk = l >> 4;

  bf16x8 aq[2];
  {
    const __hip_bfloat16* qp = qkv + ((size_t)(b * Tv + qb + w * 16 + lr)) * 3 * Dv + h * HDv + lk * 8;
    aq[0] = *(const bf16x8*)qp;
    aq[1] = *(const bf16x8*)(qp + 32);
  }

  f32x4 o[4];
  #pragma unroll
  for (int n = 0; n < 4; ++n) o[n] = (f32x4){0.f, 0.f, 0.f, 0.f};
  float mrow[4] = {-1e30f, -1e30f, -1e30f, -1e30f};
  float lrow[4] = {0.f, 0.f, 0.f, 0.f};

  int r8 = l >> 3, c8 = l & 7;
  int nt = qb / 64 + 1;

  for (int kt = 0; kt < nt; ++kt) {
    int kbase = kt * 64;
    __syncthreads();
    #pragma unroll
    for (int e = 0; e < 2; ++e) {
      int r0 = w * 16 + e * 8;
      int rK = r0 + r8;
      int csK = c8 ^ (rK & 7);
      gld16(qkv + ((size_t)(b * Tv + kbase + rK)) * 3 * Dv + Dv + h * HDv + csK * 8,
            Ks + r0 * 64);
      gld16(vt + ((size_t)((b * Hv + h) * HDv + rK)) * Tv + kbase + csK * 8,
            Vts + r0 * 64);
    }
    __syncthreads();

    f32x4 s[4];
    #pragma unroll
    for (int n = 0; n < 4; ++n) s[n] = (f32x4){0.f, 0.f, 0.f, 0.f};
    #pragma unroll
    for (int kf = 0; kf < 2; ++kf)
      #pragma unroll
      for (int nf = 0; nf < 4; ++nf) {
        int row = nf * 16 + lr;
        int g = (kf * 4 + lk) ^ (row & 7);
        bf16x8 bk = *(const bf16x8*)(Ks + row * 64 + g * 8);
        s[nf] = __builtin_amdgcn_mfma_f32_16x16x32_bf16(aq[kf], bk, s[nf], 0, 0, 0);
      }
    #pragma unroll
    for (int nf = 0; nf < 4; ++nf)
      #pragma unroll
      for (int j = 0; j < 4; ++j) s[nf][j] *= 0.125f;

    if (kt == nt - 1) {
      #pragma unroll
      for (int nf = 0; nf < 4; ++nf) {
        int kl = nf * 16 + lr;
        #pragma unroll
        for (int j = 0; j < 4; ++j)
          if (kl > w * 16 + lk * 4 + j) s[nf][j] = -1e30f;
      }
    }

    float sc[4];
    #pragma unroll
    for (int j = 0; j < 4; ++j) {
      float pm = fmaxf(fmaxf(s[0][j], s[1][j]), fmaxf(s[2][j], s[3][j]));
      pm = fmaxf(pm, __shfl_xor(pm, 1, 64));
      pm = fmaxf(pm, __shfl_xor(pm, 2, 64));
      pm = fmaxf(pm, __shfl_xor(pm, 4, 64));
      pm = fmaxf(pm, __shfl_xor(pm, 8, 64));
      float mn = fmaxf(mrow[j], pm);
      sc[j] = __expf(mrow[j] - mn);
      mrow[j] = mn;
    }
    #pragma unroll
    for (int j = 0; j < 4; ++j) {
      float ls = 0.f;
      #pragma unroll
      for (int nf = 0; nf < 4; ++nf) {
        float p = __expf(s[nf][j] - mrow[j]);
        s[nf][j] = p;
        ls += p;
      }
      ls += __shfl_xor(ls, 1, 64);
      ls += __shfl_xor(ls, 2, 64);
      ls += __shfl_xor(ls, 4, 64);
      ls += __shfl_xor(ls, 8, 64);
      lrow[j] = lrow[j] * sc[j] + ls;
    }
    #pragma unroll
    for (int n = 0; n < 4; ++n)
      #pragma unroll
      for (int j = 0; j < 4; ++j) o[n][j] *= sc[j];

    short* pw = Ps[w];
    #pragma unroll
    for (int nf = 0; nf < 4; ++nf)
      #pragma unroll
      for (int j = 0; j < 4; ++j) {
        int ql = lk * 4 + j, k = nf * 16 + lr;
        pw[ql * 64 + (((k >> 3) ^ (ql & 7)) * 8) + (k & 7)] = f2bf(s[nf][j]);
      }
    bf16x8 pa[2];
    #pragma unroll
    for (int kf = 0; kf < 2; ++kf) {
      int g = (kf * 4 + lk) ^ (lr & 7);
      pa[kf] = *(const bf16x8*)(pw + lr * 64 + g * 8);
    }
    #pragma unroll
    for (int kf = 0; kf < 2; ++kf)
      #pragma unroll
      for (int nf = 0; nf < 4; ++nf) {
        int d = nf * 16 + lr;
        int g = (kf * 4 + lk) ^ (d & 7);
        bf16x8 bv = *(const bf16x8*)(Vts + d * 64 + g * 8);
        o[nf] = __builtin_amdgcn_mfma_f32_16x16x32_bf16(pa[kf], bv, o[nf], 0, 0, 0);
      }
  }

  #pragma unroll
  for (int j = 0; j < 4; ++j) lrow[j] = 1.f / lrow[j];
  #pragma unroll
  for (int nf = 0; nf < 4; ++nf)
    #pragma unroll
    for (int j = 0; j < 4; ++j) {
      size_t oidx = ((size_t)(b * Tv + qb + w * 16 + lk * 4 + j)) * Dv + h * HDv + nf * 16 + lr;
      y[oidx] = __float2bfloat16(o[nf][j] * lrow[j]);
    }
}

extern "C" void kernel_launch(void* const* d_in, const int* in_sizes, int n_in,
                              void* d_out, int out_size, void* d_ws, size_t ws_size,
                              hipStream_t stream) {
  const int*   idx      = (const int*)  d_in[0];
  const float* wte      = (const float*)d_in[1];
  const float* wpe      = (const float*)d_in[2];
  const float* ln1_w    = (const float*)d_in[3];
  const float* ln1_b    = (const float*)d_in[4];
  const float* attn_w   = (const float*)d_in[5];
  const float* attn_b   = (const float*)d_in[6];
  const float* proj_w   = (const float*)d_in[7];
  const float* proj_b   = (const float*)d_in[8];
  const float* ln2_w    = (const float*)d_in[9];
  const float* ln2_b    = (const float*)d_in[10];
  const float* fc_w     = (const float*)d_in[11];
  const float* fc_b     = (const float*)d_in[12];
  const float* fcproj_w = (const float*)d_in[13];
  const float* fcproj_b = (const float*)d_in[14];
  const float* lnf_w    = (const float*)d_in[15];
  const float* lnf_b    = (const float*)d_in[16];
  const float* head_w   = (const float*)d_in[17];
  float* outp = (float*)d_out;

  char* w8 = (char*)d_ws;
  float*          x    = (float*)w8;                          // 2048*768 f32
  __hip_bfloat16* h    = (__hip_bfloat16*)(w8 + 6291456);     // 2048*768 bf16
  __hip_bfloat16* qkv  = (__hip_bfloat16*)(w8 + 9437184);     // 2048*2304 bf16
  __hip_bfloat16* m4   = qkv;                                 // 2048*3072 bf16 alias
  __hip_bfloat16* y    = (__hip_bfloat16*)(w8 + 22020096);    // 2048*768 bf16
  __hip_bfloat16* vt   = (__hip_bfloat16*)(w8 + 25165824);    // B*H*64*1024 bf16
  __hip_bfloat16* wbuf = (__hip_bfloat16*)(w8 + 28311552);    // weight staging

  __hip_bfloat16* wb_attn   = wbuf;                            // 768*2304
  __hip_bfloat16* wb_proj   = wb_attn + (size_t)768 * 2304;    // 768*768
  __hip_bfloat16* wb_fc     = wb_proj + (size_t)768 * 768;     // 768*3072
  __hip_bfloat16* wb_fcproj = wb_fc   + (size_t)768 * 3072;    // 3072*768

  embed_kernel<<<(MROWS * Dv / 4 + 255) / 256, 256, 0, stream>>>(idx, wte, wpe, x);

  for (int l = 0; l < Lv; ++l) {
    ln_kernel<<<MROWS, 256, 0, stream>>>(x, ln1_w + (size_t)l * Dv, ln1_b + (size_t)l * Dv, h);

    tcast4_kernel<<<6912, 256, 0, stream>>>(
        attn_w   + (size_t)l * Dv * 3 * Dv,
        proj_w   + (size_t)l * Dv * Dv,
        fc_w     + (size_t)l * Dv * 4 * Dv,
        fcproj_w + (size_t)l * 4 * Dv * Dv,
        wb_attn, wb_proj, wb_fc, wb_fcproj);

    gemm_kernel<false, true><<<dim3(MROWS / 128, 3 * Dv / 128), 256, 0, stream>>>(
        h, wb_attn, attn_b + (size_t)l * 3 * Dv, nullptr, qkv, MROWS, 3 * Dv, Dv);

    vtr_kernel<<<dim3(Tv / 64, Hv, Bv), 256, 0, stream>>>(qkv, vt);
    attn_kernel<<<dim3(Tv / 64, Hv, Bv), 256, 0, stream>>>(qkv, vt, y);

    gemm64_kernel<<<dim3(MROWS / 64, Dv / 64), 256, 0, stream>>>(
        y, wb_proj, proj_b + (size_t)l * Dv, x, x, MROWS, Dv, Dv);

    ln_kernel<<<MROWS, 256, 0, stream>>>(x, ln2_w + (size_t)l * Dv, ln2_b + (size_t)l * Dv, h);

    gemm_kernel<true, true><<<dim3(MROWS / 128, 4 * Dv / 128), 256, 0, stream>>>(
        h, wb_fc, fc_b + (size_t)l * 4 * Dv, nullptr, m4, MROWS, 4 * Dv, Dv);

    gemm64_kernel<<<dim3(MROWS / 64, Dv / 64), 256, 0, stream>>>(
        m4, wb_fcproj, fcproj_b + (size_t)l * Dv, x, x, MROWS, Dv, 4 * Dv);
  }

  ln_kernel<<<MROWS, 256, 0, stream>>>(x, lnf_w, lnf_b, h);
  tcast_kernel<<<dim3(Vv / 32, Dv / 32), 256, 0, stream>>>(head_w, wbuf, Dv, Vv);
  gemm_kernel<false, false><<<dim3(MROWS / 128, Vv / 128), 256, 0, stream>>>(
      h, wbuf, nullptr, nullptr, outp, MROWS, Vv, Dv);
}

// Round 6
// 1134.715 us; speedup vs baseline: 6.7349x; 1.0570x over previous
//
#include <hip/hip_runtime.h>
#include <hip/hip_bf16.h>
#include <math.h>

static constexpr int Bv = 2, Tv = 1024, Dv = 768, Hv = 12, Lv = 6, Vv = 32000, HDv = 64;
static constexpr int MROWS = Bv * Tv;   // 2048

typedef __attribute__((ext_vector_type(8))) short bf16x8;
typedef __attribute__((ext_vector_type(8))) short short8;
typedef __attribute__((ext_vector_type(4))) short short4v;
typedef __attribute__((ext_vector_type(4))) float f32x4;

typedef __attribute__((address_space(1))) const void gvoid;
typedef __attribute__((address_space(3))) void svoid;
__device__ __forceinline__ void gld16(const void* g, void* s) {
  __builtin_amdgcn_global_load_lds((gvoid*)g, (svoid*)s, 16, 0, 0);
}
__device__ __forceinline__ short f2bf(float v) {
  __hip_bfloat16 hb = __float2bfloat16(v);
  return *reinterpret_cast<short*>(&hb);
}
// bijective XCD-chunk remap (m204)
__device__ __forceinline__ int xcd_remap(int lin, int nwg) {
  int q = nwg >> 3, r = nwg & 7;
  int xcd = lin & 7, idx = lin >> 3;
  return (xcd < r ? xcd * (q + 1) : r * (q + 1) + (xcd - r) * q) + idx;
}

// ---------------- embedding ----------------
__global__ __launch_bounds__(256) void embed_kernel(const int* __restrict__ idx,
                                                    const float* __restrict__ wte,
                                                    const float* __restrict__ wpe,
                                                    float* __restrict__ x) {
  int i4 = blockIdx.x * 256 + threadIdx.x;
  int total = MROWS * Dv / 4;
  if (i4 >= total) return;
  int d4 = (i4 % (Dv / 4)) * 4;
  int bt = i4 / (Dv / 4);
  int t  = bt % Tv;
  int id = idx[bt];
  float4 a = *(const float4*)(wte + (size_t)id * Dv + d4);
  float4 p = *(const float4*)(wpe + (size_t)t  * Dv + d4);
  a.x += p.x; a.y += p.y; a.z += p.z; a.w += p.w;
  *(float4*)(x + (size_t)bt * Dv + d4) = a;
}

// ---------------- layernorm: fp32 in -> bf16 out ----------------
__global__ __launch_bounds__(256) void ln_kernel(const float* __restrict__ x,
                                                 const float* __restrict__ w,
                                                 const float* __restrict__ b,
                                                 __hip_bfloat16* __restrict__ out) {
  int row = blockIdx.x;
  const float* xr = x + (size_t)row * Dv;
  int tid = threadIdx.x;
  float v0 = xr[tid], v1 = xr[tid + 256], v2 = xr[tid + 512];
  __shared__ float red[8];
  int wid = tid >> 6, lane = tid & 63;

  float s = v0 + v1 + v2;
  #pragma unroll
  for (int off = 1; off < 64; off <<= 1) s += __shfl_xor(s, off, 64);
  if (lane == 0) red[wid] = s;
  __syncthreads();
  s = red[0] + red[1] + red[2] + red[3];
  float mu = s * (1.0f / Dv);

  float d0 = v0 - mu, d1 = v1 - mu, d2 = v2 - mu;
  float q = d0 * d0 + d1 * d1 + d2 * d2;
  #pragma unroll
  for (int off = 1; off < 64; off <<= 1) q += __shfl_xor(q, off, 64);
  if (lane == 0) red[4 + wid] = q;
  __syncthreads();
  q = red[4] + red[5] + red[6] + red[7];
  float rs = rsqrtf(q * (1.0f / Dv) + 1e-5f);

  __hip_bfloat16* orow = out + (size_t)row * Dv;
  orow[tid]       = __float2bfloat16(d0 * rs * w[tid]       + b[tid]);
  orow[tid + 256] = __float2bfloat16(d1 * rs * w[tid + 256] + b[tid + 256]);
  orow[tid + 512] = __float2bfloat16(d2 * rs * w[tid + 512] + b[tid + 512]);
}

// ---------------- transpose+cast body ----------------
__device__ __forceinline__ void tcast_body(const float* __restrict__ W,
                                           __hip_bfloat16* __restrict__ Wt,
                                           int K, int N, int k0, int n0) {
  __shared__ float tile[32][33];
  int tx = threadIdx.x & 31, ty = threadIdx.x >> 5;
  #pragma unroll
  for (int r = 0; r < 32; r += 8)
    tile[ty + r][tx] = W[(size_t)(k0 + ty + r) * N + n0 + tx];
  __syncthreads();
  #pragma unroll
  for (int r = 0; r < 32; r += 8)
    Wt[(size_t)(n0 + ty + r) * K + k0 + tx] = __float2bfloat16(tile[tx][ty + r]);
}

__global__ __launch_bounds__(256) void tcast_kernel(const float* __restrict__ W,
                                                    __hip_bfloat16* __restrict__ Wt,
                                                    int K, int N) {
  tcast_body(W, Wt, K, N, blockIdx.y * 32, blockIdx.x * 32);
}

__global__ __launch_bounds__(256) void tcast4_kernel(const float* __restrict__ s0,
                                                     const float* __restrict__ s1,
                                                     const float* __restrict__ s2,
                                                     const float* __restrict__ s3,
                                                     __hip_bfloat16* __restrict__ d0,
                                                     __hip_bfloat16* __restrict__ d1,
                                                     __hip_bfloat16* __restrict__ d2,
                                                     __hip_bfloat16* __restrict__ d3) {
  int lin = blockIdx.x;
  const float* W; __hip_bfloat16* Wt; int K, N, loc;
  if (lin < 1728)      { W = s0; Wt = d0; K = 768;  N = 2304; loc = lin; }
  else if (lin < 2304) { W = s1; Wt = d1; K = 768;  N = 768;  loc = lin - 1728; }
  else if (lin < 4608) { W = s2; Wt = d2; K = 768;  N = 3072; loc = lin - 2304; }
  else                 { W = s3; Wt = d3; K = 3072; N = 768;  loc = lin - 4608; }
  int nb = N / 32;
  tcast_body(W, Wt, K, N, (loc / nb) * 32, (loc % nb) * 32);
}

// ---------------- 128x128 MFMA GEMM (BK=32) -------------------------------
// VT: for qkv GEMM, also scatter V columns transposed into vt[b,h,d,t].
template <bool GELU, bool OBF, bool VT>
__global__ __launch_bounds__(256) void gemm_kernel(const __hip_bfloat16* __restrict__ A,
                                                   const __hip_bfloat16* __restrict__ Wt,
                                                   const float* __restrict__ bias,
                                                   const float* __restrict__ resid,
                                                   void* __restrict__ outv,
                                                   __hip_bfloat16* __restrict__ vt,
                                                   int M, int N, int K) {
  __shared__ short As[128 * 32];
  __shared__ short Bs[128 * 32];
  int nwg = gridDim.x * gridDim.y;
  int wgid = xcd_remap(blockIdx.y * gridDim.x + blockIdx.x, nwg);
  int m0 = (wgid % gridDim.x) * 128, n0 = (wgid / gridDim.x) * 128;

  int tid = threadIdx.x;
  int w = tid >> 6, lane = tid & 63;
  int wr = w >> 1, wc = w & 1;

  f32x4 acc[4][4];
  #pragma unroll
  for (int m = 0; m < 4; ++m)
    #pragma unroll
    for (int n = 0; n < 4; ++n) acc[m][n] = (f32x4){0.f, 0.f, 0.f, 0.f};

  int lr = lane & 15, lk = lane >> 4;
  const short* abase = As + (wr * 64 + lr) * 32 + lk * 8;
  const short* bbase = Bs + (wc * 64 + lr) * 32 + lk * 8;
  int ko = (lane & 3) * 8;
  int rsub = lane >> 2;

  for (int k0 = 0; k0 < K; k0 += 32) {
    __syncthreads();
    #pragma unroll
    for (int e = 0; e < 2; ++e) {
      int chunk = e * 4 + w;
      int row = chunk * 16 + rsub;
      gld16(A  + (size_t)(m0 + row) * K + k0 + ko, As + chunk * 512);
      gld16(Wt + (size_t)(n0 + row) * K + k0 + ko, Bs + chunk * 512);
    }
    __syncthreads();
    bf16x8 af[4], bf[4];
    #pragma unroll
    for (int m = 0; m < 4; ++m) af[m] = *(const bf16x8*)(abase + m * 512);
    #pragma unroll
    for (int n = 0; n < 4; ++n) bf[n] = *(const bf16x8*)(bbase + n * 512);
    #pragma unroll
    for (int m = 0; m < 4; ++m)
      #pragma unroll
      for (int n = 0; n < 4; ++n)
        acc[m][n] = __builtin_amdgcn_mfma_f32_16x16x32_bf16(af[m], bf[n], acc[m][n], 0, 0, 0);
  }

  int row0 = m0 + wr * 64, col0 = n0 + wc * 64;
  float* outf = (float*)outv;
  __hip_bfloat16* outb = (__hip_bfloat16*)outv;
  #pragma unroll
  for (int n = 0; n < 4; ++n) {
    int col = col0 + n * 16 + lr;
    float bv = bias ? bias[col] : 0.f;
    #pragma unroll
    for (int m = 0; m < 4; ++m) {
      int rbase = row0 + m * 16 + lk * 4;
      float r4[4];
      #pragma unroll
      for (int j = 0; j < 4; ++j) {
        float v = acc[m][n][j] + bv;
        if (GELU) v = 0.5f * v * (1.0f + erff(v * 0.70710678118f));
        size_t o = (size_t)(rbase + j) * N + col;
        if (resid) v += resid[o];
        r4[j] = v;
        if (OBF) outb[o] = __float2bfloat16(v);
        else     outf[o] = v;
      }
      if (VT && col >= 2 * Dv) {
        int hh = (col - 2 * Dv) >> 6, dd = (col - 2 * Dv) & 63;
        int bb = rbase >> 10, t0 = rbase & 1023;
        short4v pk = {f2bf(r4[0]), f2bf(r4[1]), f2bf(r4[2]), f2bf(r4[3])};
        *(short4v*)(vt + (((size_t)(bb * Hv + hh) * HDv + dd) << 10) + t0) = pk;
      }
    }
  }
}

// ---------------- 64x64 MFMA GEMM (BK=64, XOR-swizzled LDS) ----------------
__global__ __launch_bounds__(256) void gemm64_kernel(const __hip_bfloat16* __restrict__ A,
                                                     const __hip_bfloat16* __restrict__ Wt,
                                                     const float* __restrict__ bias,
                                                     const float* __restrict__ resid,
                                                     float* __restrict__ out,
                                                     int M, int N, int K) {
  __shared__ short As[64 * 64];
  __shared__ short Bs[64 * 64];
  int nwg = gridDim.x * gridDim.y;
  int wgid = xcd_remap(blockIdx.y * gridDim.x + blockIdx.x, nwg);
  int m0 = (wgid % gridDim.x) * 64, n0 = (wgid / gridDim.x) * 64;

  int tid = threadIdx.x;
  int w = tid >> 6, lane = tid & 63;
  int wr = w >> 1, wc = w & 1;

  f32x4 acc[2][2];
  #pragma unroll
  for (int m = 0; m < 2; ++m)
    #pragma unroll
    for (int n = 0; n < 2; ++n) acc[m][n] = (f32x4){0.f, 0.f, 0.f, 0.f};

  int lr = lane & 15, lk = lane >> 4;
  int rsub = lane >> 3, go = lane & 7;

  for (int k0 = 0; k0 < K; k0 += 64) {
    __syncthreads();
    #pragma unroll
    for (int e = 0; e < 2; ++e) {
      int row = w * 16 + e * 8 + rsub;
      int gs = (go ^ rsub) * 8;
      gld16(A  + (size_t)(m0 + row) * K + k0 + gs, As + w * 1024 + e * 512);
      gld16(Wt + (size_t)(n0 + row) * K + k0 + gs, Bs + w * 1024 + e * 512);
    }
    __syncthreads();
    #pragma unroll
    for (int kf = 0; kf < 2; ++kf) {
      bf16x8 af[2], bf[2];
      #pragma unroll
      for (int m = 0; m < 2; ++m) {
        int row = wr * 32 + m * 16 + lr;
        af[m] = *(const bf16x8*)(As + row * 64 + (((kf * 4 + lk) ^ (row & 7)) * 8));
      }
      #pragma unroll
      for (int n = 0; n < 2; ++n) {
        int row = wc * 32 + n * 16 + lr;
        bf[n] = *(const bf16x8*)(Bs + row * 64 + (((kf * 4 + lk) ^ (row & 7)) * 8));
      }
      #pragma unroll
      for (int m = 0; m < 2; ++m)
        #pragma unroll
        for (int n = 0; n < 2; ++n)
          acc[m][n] = __builtin_amdgcn_mfma_f32_16x16x32_bf16(af[m], bf[n], acc[m][n], 0, 0, 0);
    }
  }

  int row0 = m0 + wr * 32, col0 = n0 + wc * 32;
  #pragma unroll
  for (int n = 0; n < 2; ++n) {
    int col = col0 + n * 16 + lr;
    float bv = bias ? bias[col] : 0.f;
    #pragma unroll
    for (int m = 0; m < 2; ++m) {
      int rbase = row0 + m * 16 + lk * 4;
      #pragma unroll
      for (int j = 0; j < 4; ++j) {
        float v = acc[m][n][j] + bv;
        size_t o = (size_t)(rbase + j) * N + col;
        if (resid) v += resid[o];
        out[o] = v;
      }
    }
  }
}

// ---------------- 256x256 8-phase counted-vmcnt GEMM (head) ---------------
// Stage stream per tile: {A.h0, B.h0, B.h1, A.h1} issued at prev-tile phases
// 0..3. Per-phase: stage(2 gld16) -> vmcnt(4) -> 12 ds_read_b128 -> barrier
// -> 16 MFMA (setprio) -> barrier.
// LEDGER FIX (round 5 bug): phases beyond the last tile must STILL issue 2
// loads each, else outstanding stays at 4 and vmcnt(4) stops retiring the
// final tile's B1/A1 halves -> race. Phantom stages re-load tile NT-1 into
// the dead opposite buffer (never read; its readers finished a tile ago).
__global__ __launch_bounds__(512, 2) void gemm256_kernel(const __hip_bfloat16* __restrict__ A,
                                                         const __hip_bfloat16* __restrict__ Wt,
                                                         float* __restrict__ out,
                                                         int N, int K) {
  __shared__ short lds[65536];   // 128 KB
  int nwg = gridDim.x * gridDim.y;
  int wgid = xcd_remap(blockIdx.y * gridDim.x + blockIdx.x, nwg);
  int m0 = (wgid % gridDim.x) * 256, n0 = (wgid / gridDim.x) * 256;

  int tid = threadIdx.x;
  int w = tid >> 6, lane = tid & 63;
  int wr = w >> 2, wc = w & 3;          // 2 x 4 waves
  int lr = lane & 15, lk = lane >> 4;

  f32x4 acc[8][4];
  #pragma unroll
  for (int m = 0; m < 8; ++m)
    #pragma unroll
    for (int n = 0; n < 4; ++n) acc[m][n] = (f32x4){0.f, 0.f, 0.f, 0.f};

  int NT = K >> 6;

  // half h: 0 = A rows 0-127, 1 = B rows 0-127, 2 = B rows 128-255, 3 = A rows 128-255
  auto stage = [&](int tau, int h) {
    int tsrc = tau < NT ? tau : NT - 1;       // phantom: re-read last tile
    const __hip_bfloat16* mat;
    size_t rb; int lofs;
    if (h == 0)      { mat = A;  rb = (size_t)m0;       lofs = 0; }
    else if (h == 1) { mat = Wt; rb = (size_t)n0;       lofs = 16384; }
    else if (h == 2) { mat = Wt; rb = (size_t)n0 + 128; lofs = 24576; }
    else             { mat = A;  rb = (size_t)m0 + 128; lofs = 8192; }
    short* lb = lds + (tau & 1) * 32768 + lofs;   // parity of REQUESTED tile
    #pragma unroll
    for (int e = 0; e < 2; ++e) {
      int idx = e * 512 + tid;
      int r = idx >> 3, g = idx & 7;
      gld16(mat + (rb + r) * (size_t)K + tsrc * 64 + ((g ^ (r & 7)) * 8), lb + idx * 8);
    }
  };

  // prologue: tile 0 fully staged; A0,B0 retired before first reads
  stage(0, 0); stage(0, 1); stage(0, 2); stage(0, 3);
  asm volatile("s_waitcnt vmcnt(4)" ::: "memory");
  asm volatile("s_barrier" ::: "memory");

  for (int tau = 0; tau < NT; ++tau) {
    const short* bufA = lds + (tau & 1) * 32768;
    const short* bufB = bufA + 16384;
    #pragma unroll
    for (int q = 0; q < 4; ++q) {
      stage(tau + 1, q);
      asm volatile("s_waitcnt vmcnt(4)" ::: "memory");
      int qm = q >> 1, qn = q & 1;
      const short* ab = bufA + qm * 8192;
      const short* bb = bufB + qn * 8192;
      bf16x8 af[4][2], bf[2][2];
      #pragma unroll
      for (int mi = 0; mi < 4; ++mi) {
        int ra = wr * 64 + mi * 16 + lr;
        #pragma unroll
        for (int kf = 0; kf < 2; ++kf)
          af[mi][kf] = *(const bf16x8*)(ab + ra * 64 + (((kf * 4 + lk) ^ (ra & 7)) * 8));
      }
      #pragma unroll
      for (int ni = 0; ni < 2; ++ni) {
        int rb2 = wc * 32 + ni * 16 + lr;
        #pragma unroll
        for (int kf = 0; kf < 2; ++kf)
          bf[ni][kf] = *(const bf16x8*)(bb + rb2 * 64 + (((kf * 4 + lk) ^ (rb2 & 7)) * 8));
      }
      asm volatile("s_barrier" ::: "memory");
      __builtin_amdgcn_s_setprio(1);
      #pragma unroll
      for (int mi = 0; mi < 4; ++mi)
        #pragma unroll
        for (int ni = 0; ni < 2; ++ni)
          #pragma unroll
          for (int kf = 0; kf < 2; ++kf)
            acc[qm * 4 + mi][qn * 2 + ni] = __builtin_amdgcn_mfma_f32_16x16x32_bf16(
                af[mi][kf], bf[ni][kf], acc[qm * 4 + mi][qn * 2 + ni], 0, 0, 0);
      __builtin_amdgcn_s_setprio(0);
      asm volatile("s_barrier" ::: "memory");
    }
  }

  #pragma unroll
  for (int gm = 0; gm < 8; ++gm) {
    int row = m0 + (gm >> 2) * 128 + wr * 64 + (gm & 3) * 16 + lk * 4;
    #pragma unroll
    for (int gn = 0; gn < 4; ++gn) {
      int col = n0 + (gn >> 1) * 128 + wc * 32 + (gn & 1) * 16 + lr;
      #pragma unroll
      for (int j = 0; j < 4; ++j)
        out[(size_t)(row + j) * N + col] = acc[gm][gn][j];
    }
  }
}

// ---------------- MFMA flash attention ----------------
__global__ __launch_bounds__(256) void attn_kernel(const __hip_bfloat16* __restrict__ qkv,
                                                   const __hip_bfloat16* __restrict__ vt,
                                                   __hip_bfloat16* __restrict__ y) {
  __shared__ short Ks[64 * 64];
  __shared__ short Vts[64 * 64];
  __shared__ short Ps[4][16 * 64];
  int b = blockIdx.z, h = blockIdx.y;
  int qb = (gridDim.x - 1 - blockIdx.x) * 64;
  int tid = threadIdx.x;
  int w = tid >> 6, l = tid & 63;
  int lr = l & 15, lk = l >> 4;

  bf16x8 aq[2];
  {
    const __hip_bfloat16* qp = qkv + ((size_t)(b * Tv + qb + w * 16 + lr)) * 3 * Dv + h * HDv + lk * 8;
    aq[0] = *(const bf16x8*)qp;
    aq[1] = *(const bf16x8*)(qp + 32);
  }

  f32x4 o[4];
  #pragma unroll
  for (int n = 0; n < 4; ++n) o[n] = (f32x4){0.f, 0.f, 0.f, 0.f};
  float mrow[4] = {-1e30f, -1e30f, -1e30f, -1e30f};
  float lrow[4] = {0.f, 0.f, 0.f, 0.f};

  int r8 = l >> 3, c8 = l & 7;
  int nt = qb / 64 + 1;

  for (int kt = 0; kt < nt; ++kt) {
    int kbase = kt * 64;
    __syncthreads();
    #pragma unroll
    for (int e = 0; e < 2; ++e) {
      int r0 = w * 16 + e * 8;
      int rK = r0 + r8;
      int csK = c8 ^ (rK & 7);
      gld16(qkv + ((size_t)(b * Tv + kbase + rK)) * 3 * Dv + Dv + h * HDv + csK * 8,
            Ks + r0 * 64);
      gld16(vt + ((size_t)((b * Hv + h) * HDv + rK)) * Tv + kbase + csK * 8,
            Vts + r0 * 64);
    }
    __syncthreads();

    f32x4 s[4];
    #pragma unroll
    for (int n = 0; n < 4; ++n) s[n] = (f32x4){0.f, 0.f, 0.f, 0.f};
    #pragma unroll
    for (int kf = 0; kf < 2; ++kf)
      #pragma unroll
      for (int nf = 0; nf < 4; ++nf) {
        int row = nf * 16 + lr;
        int g = (kf * 4 + lk) ^ (row & 7);
        bf16x8 bk = *(const bf16x8*)(Ks + row * 64 + g * 8);
        s[nf] = __builtin_amdgcn_mfma_f32_16x16x32_bf16(aq[kf], bk, s[nf], 0, 0, 0);
      }
    #pragma unroll
    for (int nf = 0; nf < 4; ++nf)
      #pragma unroll
      for (int j = 0; j < 4; ++j) s[nf][j] *= 0.125f;

    if (kt == nt - 1) {
      #pragma unroll
      for (int nf = 0; nf < 4; ++nf) {
        int kl = nf * 16 + lr;
        #pragma unroll
        for (int j = 0; j < 4; ++j)
          if (kl > w * 16 + lk * 4 + j) s[nf][j] = -1e30f;
      }
    }

    float sc[4];
    #pragma unroll
    for (int j = 0; j < 4; ++j) {
      float pm = fmaxf(fmaxf(s[0][j], s[1][j]), fmaxf(s[2][j], s[3][j]));
      pm = fmaxf(pm, __shfl_xor(pm, 1, 64));
      pm = fmaxf(pm, __shfl_xor(pm, 2, 64));
      pm = fmaxf(pm, __shfl_xor(pm, 4, 64));
      pm = fmaxf(pm, __shfl_xor(pm, 8, 64));
      float mn = fmaxf(mrow[j], pm);
      sc[j] = __expf(mrow[j] - mn);
      mrow[j] = mn;
    }
    #pragma unroll
    for (int j = 0; j < 4; ++j) {
      float ls = 0.f;
      #pragma unroll
      for (int nf = 0; nf < 4; ++nf) {
        float p = __expf(s[nf][j] - mrow[j]);
        s[nf][j] = p;
        ls += p;
      }
      ls += __shfl_xor(ls, 1, 64);
      ls += __shfl_xor(ls, 2, 64);
      ls += __shfl_xor(ls, 4, 64);
      ls += __shfl_xor(ls, 8, 64);
      lrow[j] = lrow[j] * sc[j] + ls;
    }
    #pragma unroll
    for (int n = 0; n < 4; ++n)
      #pragma unroll
      for (int j = 0; j < 4; ++j) o[n][j] *= sc[j];

    short* pw = Ps[w];
    #pragma unroll
    for (int nf = 0; nf < 4; ++nf)
      #pragma unroll
      for (int j = 0; j < 4; ++j) {
        int ql = lk * 4 + j, k = nf * 16 + lr;
        pw[ql * 64 + (((k >> 3) ^ (ql & 7)) * 8) + (k & 7)] = f2bf(s[nf][j]);
      }
    bf16x8 pa[2];
    #pragma unroll
    for (int kf = 0; kf < 2; ++kf) {
      int g = (kf * 4 + lk) ^ (lr & 7);
      pa[kf] = *(const bf16x8*)(pw + lr * 64 + g * 8);
    }
    #pragma unroll
    for (int kf = 0; kf < 2; ++kf)
      #pragma unroll
      for (int nf = 0; nf < 4; ++nf) {
        int d = nf * 16 + lr;
        int g = (kf * 4 + lk) ^ (d & 7);
        bf16x8 bv = *(const bf16x8*)(Vts + d * 64 + g * 8);
        o[nf] = __builtin_amdgcn_mfma_f32_16x16x32_bf16(pa[kf], bv, o[nf], 0, 0, 0);
      }
  }

  #pragma unroll
  for (int j = 0; j < 4; ++j) lrow[j] = 1.f / lrow[j];
  #pragma unroll
  for (int nf = 0; nf < 4; ++nf)
    #pragma unroll
    for (int j = 0; j < 4; ++j) {
      size_t oidx = ((size_t)(b * Tv + qb + w * 16 + lk * 4 + j)) * Dv + h * HDv + nf * 16 + lr;
      y[oidx] = __float2bfloat16(o[nf][j] * lrow[j]);
    }
}

extern "C" void kernel_launch(void* const* d_in, const int* in_sizes, int n_in,
                              void* d_out, int out_size, void* d_ws, size_t ws_size,
                              hipStream_t stream) {
  const int*   idx      = (const int*)  d_in[0];
  const float* wte      = (const float*)d_in[1];
  const float* wpe      = (const float*)d_in[2];
  const float* ln1_w    = (const float*)d_in[3];
  const float* ln1_b    = (const float*)d_in[4];
  const float* attn_w   = (const float*)d_in[5];
  const float* attn_b   = (const float*)d_in[6];
  const float* proj_w   = (const float*)d_in[7];
  const float* proj_b   = (const float*)d_in[8];
  const float* ln2_w    = (const float*)d_in[9];
  const float* ln2_b    = (const float*)d_in[10];
  const float* fc_w     = (const float*)d_in[11];
  const float* fc_b     = (const float*)d_in[12];
  const float* fcproj_w = (const float*)d_in[13];
  const float* fcproj_b = (const float*)d_in[14];
  const float* lnf_w    = (const float*)d_in[15];
  const float* lnf_b    = (const float*)d_in[16];
  const float* head_w   = (const float*)d_in[17];
  float* outp = (float*)d_out;

  char* w8 = (char*)d_ws;
  float*          x    = (float*)w8;                          // 2048*768 f32
  __hip_bfloat16* h    = (__hip_bfloat16*)(w8 + 6291456);     // 2048*768 bf16
  __hip_bfloat16* qkv  = (__hip_bfloat16*)(w8 + 9437184);     // 2048*2304 bf16
  __hip_bfloat16* m4   = qkv;                                 // 2048*3072 bf16 alias
  __hip_bfloat16* y    = (__hip_bfloat16*)(w8 + 22020096);    // 2048*768 bf16
  __hip_bfloat16* vt   = (__hip_bfloat16*)(w8 + 25165824);    // B*H*64*1024 bf16
  __hip_bfloat16* wbuf = (__hip_bfloat16*)(w8 + 28311552);    // weight staging

  __hip_bfloat16* wb_attn   = wbuf;
  __hip_bfloat16* wb_proj   = wb_attn + (size_t)768 * 2304;
  __hip_bfloat16* wb_fc     = wb_proj + (size_t)768 * 768;
  __hip_bfloat16* wb_fcproj = wb_fc   + (size_t)768 * 3072;

  embed_kernel<<<(MROWS * Dv / 4 + 255) / 256, 256, 0, stream>>>(idx, wte, wpe, x);

  for (int l = 0; l < Lv; ++l) {
    ln_kernel<<<MROWS, 256, 0, stream>>>(x, ln1_w + (size_t)l * Dv, ln1_b + (size_t)l * Dv, h);

    tcast4_kernel<<<6912, 256, 0, stream>>>(
        attn_w   + (size_t)l * Dv * 3 * Dv,
        proj_w   + (size_t)l * Dv * Dv,
        fc_w     + (size_t)l * Dv * 4 * Dv,
        fcproj_w + (size_t)l * 4 * Dv * Dv,
        wb_attn, wb_proj, wb_fc, wb_fcproj);

    gemm_kernel<false, true, true><<<dim3(MROWS / 128, 3 * Dv / 128), 256, 0, stream>>>(
        h, wb_attn, attn_b + (size_t)l * 3 * Dv, nullptr, qkv, vt, MROWS, 3 * Dv, Dv);

    attn_kernel<<<dim3(Tv / 64, Hv, Bv), 256, 0, stream>>>(qkv, vt, y);

    gemm64_kernel<<<dim3(MROWS / 64, Dv / 64), 256, 0, stream>>>(
        y, wb_proj, proj_b + (size_t)l * Dv, x, x, MROWS, Dv, Dv);

    ln_kernel<<<MROWS, 256, 0, stream>>>(x, ln2_w + (size_t)l * Dv, ln2_b + (size_t)l * Dv, h);

    gemm_kernel<true, true, false><<<dim3(MROWS / 128, 4 * Dv / 128), 256, 0, stream>>>(
        h, wb_fc, fc_b + (size_t)l * 4 * Dv, nullptr, m4, nullptr, MROWS, 4 * Dv, Dv);

    gemm64_kernel<<<dim3(MROWS / 64, Dv / 64), 256, 0, stream>>>(
        m4, wb_fcproj, fcproj_b + (size_t)l * Dv, x, x, MROWS, Dv, 4 * Dv);
  }

  ln_kernel<<<MROWS, 256, 0, stream>>>(x, lnf_w, lnf_b, h);
  tcast_kernel<<<dim3(Vv / 32, Dv / 32), 256, 0, stream>>>(head_w, wbuf, Dv, Vv);
  gemm256_kernel<<<dim3(MROWS / 256, Vv / 256), 512, 0, stream>>>(
      h, wbuf, outp, Vv, Dv);
}

// Round 8
// 1081.967 us; speedup vs baseline: 7.0632x; 1.0488x over previous
//
#include <hip/hip_runtime.h>
#include <hip/hip_bf16.h>
#include <math.h>

static constexpr int Bv = 2, Tv = 1024, Dv = 768, Hv = 12, Lv = 6, Vv = 32000, HDv = 64;
static constexpr int MROWS = Bv * Tv;   // 2048

typedef __attribute__((ext_vector_type(8))) short bf16x8;
typedef __attribute__((ext_vector_type(8))) short short8;
typedef __attribute__((ext_vector_type(4))) short short4v;
typedef __attribute__((ext_vector_type(4))) float f32x4;

typedef __attribute__((address_space(1))) const void gvoid;
typedef __attribute__((address_space(3))) void svoid;
__device__ __forceinline__ void gld16(const void* g, void* s) {
  __builtin_amdgcn_global_load_lds((gvoid*)g, (svoid*)s, 16, 0, 0);
}
__device__ __forceinline__ short f2bf(float v) {
  __hip_bfloat16 hb = __float2bfloat16(v);
  return *reinterpret_cast<short*>(&hb);
}
// bijective XCD-chunk remap (m204)
__device__ __forceinline__ int xcd_remap(int lin, int nwg) {
  int q = nwg >> 3, r = nwg & 7;
  int xcd = lin & 7, idx = lin >> 3;
  return (xcd < r ? xcd * (q + 1) : r * (q + 1) + (xcd - r) * q) + idx;
}

// ---------------- embedding ----------------
__global__ __launch_bounds__(256) void embed_kernel(const int* __restrict__ idx,
                                                    const float* __restrict__ wte,
                                                    const float* __restrict__ wpe,
                                                    float* __restrict__ x) {
  int i4 = blockIdx.x * 256 + threadIdx.x;
  int total = MROWS * Dv / 4;
  if (i4 >= total) return;
  int d4 = (i4 % (Dv / 4)) * 4;
  int bt = i4 / (Dv / 4);
  int t  = bt % Tv;
  int id = idx[bt];
  float4 a = *(const float4*)(wte + (size_t)id * Dv + d4);
  float4 p = *(const float4*)(wpe + (size_t)t  * Dv + d4);
  a.x += p.x; a.y += p.y; a.z += p.z; a.w += p.w;
  *(float4*)(x + (size_t)bt * Dv + d4) = a;
}

// ---------------- layernorm: fp32 in -> bf16 out ----------------
__global__ __launch_bounds__(256) void ln_kernel(const float* __restrict__ x,
                                                 const float* __restrict__ w,
                                                 const float* __restrict__ b,
                                                 __hip_bfloat16* __restrict__ out) {
  int row = blockIdx.x;
  const float* xr = x + (size_t)row * Dv;
  int tid = threadIdx.x;
  float v0 = xr[tid], v1 = xr[tid + 256], v2 = xr[tid + 512];
  __shared__ float red[8];
  int wid = tid >> 6, lane = tid & 63;

  float s = v0 + v1 + v2;
  #pragma unroll
  for (int off = 1; off < 64; off <<= 1) s += __shfl_xor(s, off, 64);
  if (lane == 0) red[wid] = s;
  __syncthreads();
  s = red[0] + red[1] + red[2] + red[3];
  float mu = s * (1.0f / Dv);

  float d0 = v0 - mu, d1 = v1 - mu, d2 = v2 - mu;
  float q = d0 * d0 + d1 * d1 + d2 * d2;
  #pragma unroll
  for (int off = 1; off < 64; off <<= 1) q += __shfl_xor(q, off, 64);
  if (lane == 0) red[4 + wid] = q;
  __syncthreads();
  q = red[4] + red[5] + red[6] + red[7];
  float rs = rsqrtf(q * (1.0f / Dv) + 1e-5f);

  __hip_bfloat16* orow = out + (size_t)row * Dv;
  orow[tid]       = __float2bfloat16(d0 * rs * w[tid]       + b[tid]);
  orow[tid + 256] = __float2bfloat16(d1 * rs * w[tid + 256] + b[tid + 256]);
  orow[tid + 512] = __float2bfloat16(d2 * rs * w[tid + 512] + b[tid + 512]);
}

// ---------------- transpose+cast body ----------------
__device__ __forceinline__ void tcast_body(const float* __restrict__ W,
                                           __hip_bfloat16* __restrict__ Wt,
                                           int K, int N, int k0, int n0) {
  __shared__ float tile[32][33];
  int tx = threadIdx.x & 31, ty = threadIdx.x >> 5;
  #pragma unroll
  for (int r = 0; r < 32; r += 8)
    tile[ty + r][tx] = W[(size_t)(k0 + ty + r) * N + n0 + tx];
  __syncthreads();
  #pragma unroll
  for (int r = 0; r < 32; r += 8)
    Wt[(size_t)(n0 + ty + r) * K + k0 + tx] = __float2bfloat16(tile[tx][ty + r]);
}

__global__ __launch_bounds__(256) void tcast_kernel(const float* __restrict__ W,
                                                    __hip_bfloat16* __restrict__ Wt,
                                                    int K, int N) {
  tcast_body(W, Wt, K, N, blockIdx.y * 32, blockIdx.x * 32);
}

__global__ __launch_bounds__(256) void tcast4_kernel(const float* __restrict__ s0,
                                                     const float* __restrict__ s1,
                                                     const float* __restrict__ s2,
                                                     const float* __restrict__ s3,
                                                     __hip_bfloat16* __restrict__ d0,
                                                     __hip_bfloat16* __restrict__ d1,
                                                     __hip_bfloat16* __restrict__ d2,
                                                     __hip_bfloat16* __restrict__ d3) {
  int lin = blockIdx.x;
  const float* W; __hip_bfloat16* Wt; int K, N, loc;
  if (lin < 1728)      { W = s0; Wt = d0; K = 768;  N = 2304; loc = lin; }
  else if (lin < 2304) { W = s1; Wt = d1; K = 768;  N = 768;  loc = lin - 1728; }
  else if (lin < 4608) { W = s2; Wt = d2; K = 768;  N = 3072; loc = lin - 2304; }
  else                 { W = s3; Wt = d3; K = 3072; N = 768;  loc = lin - 4608; }
  int nb = N / 32;
  tcast_body(W, Wt, K, N, (loc / nb) * 32, (loc % nb) * 32);
}

// ---------------- 128x128 MFMA GEMM body: BK=64, XOR swizzle, 2-phase dbuf --
template <bool GELU, bool OBF, bool VT>
__device__ __forceinline__ void gemm128_body(const __hip_bfloat16* __restrict__ A,
                                             const __hip_bfloat16* __restrict__ Wt,
                                             const float* __restrict__ bias,
                                             const float* __restrict__ resid,
                                             void* __restrict__ outv,
                                             __hip_bfloat16* __restrict__ vt,
                                             int M, int N, int K) {
  __shared__ short As[2][8192];   // [128][64] per buf, XOR-swizzled granules
  __shared__ short Bs[2][8192];
  int nwg = gridDim.x * gridDim.y;
  int wgid = xcd_remap(blockIdx.y * gridDim.x + blockIdx.x, nwg);
  int m0 = (wgid % gridDim.x) * 128, n0 = (wgid / gridDim.x) * 128;

  int tid = threadIdx.x;
  int w = tid >> 6, lane = tid & 63;
  int wr = w >> 1, wc = w & 1;
  int lr = lane & 15, lk = lane >> 4;

  f32x4 acc[4][4];
  #pragma unroll
  for (int m = 0; m < 4; ++m)
    #pragma unroll
    for (int n = 0; n < 4; ++n) acc[m][n] = (f32x4){0.f, 0.f, 0.f, 0.f};

  auto stg = [&](int k0, int p) {
    #pragma unroll
    for (int e = 0; e < 4; ++e) {
      int idx2 = e * 256 + tid;
      int r = idx2 >> 3, g = idx2 & 7;
      int gs = (g ^ (r & 7)) * 8;               // pre-swizzled global granule
      gld16(A  + (size_t)(m0 + r) * K + k0 + gs, &As[p][idx2 * 8]);
      gld16(Wt + (size_t)(n0 + r) * K + k0 + gs, &Bs[p][idx2 * 8]);
    }
  };

  stg(0, 0);
  __syncthreads();
  int NK = K >> 6;
  for (int kt = 0; kt < NK; ++kt) {
    int p = kt & 1;
    if (kt + 1 < NK) stg((kt + 1) << 6, p ^ 1);
    bf16x8 af[4][2], bf[4][2];
    #pragma unroll
    for (int m = 0; m < 4; ++m) {
      int ra = wr * 64 + m * 16 + lr;
      #pragma unroll
      for (int kf = 0; kf < 2; ++kf)
        af[m][kf] = *(const bf16x8*)(&As[p][ra * 64 + (((kf * 4 + lk) ^ (ra & 7)) * 8)]);
    }
    #pragma unroll
    for (int n = 0; n < 4; ++n) {
      int rb = wc * 64 + n * 16 + lr;
      #pragma unroll
      for (int kf = 0; kf < 2; ++kf)
        bf[n][kf] = *(const bf16x8*)(&Bs[p][rb * 64 + (((kf * 4 + lk) ^ (rb & 7)) * 8)]);
    }
    #pragma unroll
    for (int kf = 0; kf < 2; ++kf)
      #pragma unroll
      for (int m = 0; m < 4; ++m)
        #pragma unroll
        for (int n = 0; n < 4; ++n)
          acc[m][n] = __builtin_amdgcn_mfma_f32_16x16x32_bf16(af[m][kf], bf[n][kf], acc[m][n], 0, 0, 0);
    __syncthreads();   // drains stage vmcnt + publishes next buf
  }

  int row0 = m0 + wr * 64, col0 = n0 + wc * 64;
  float* outf = (float*)outv;
  __hip_bfloat16* outb = (__hip_bfloat16*)outv;
  #pragma unroll
  for (int n = 0; n < 4; ++n) {
    int col = col0 + n * 16 + lr;
    float bv = bias ? bias[col] : 0.f;
    #pragma unroll
    for (int m = 0; m < 4; ++m) {
      int rbase = row0 + m * 16 + lk * 4;
      float r4[4];
      #pragma unroll
      for (int j = 0; j < 4; ++j) {
        float v = acc[m][n][j] + bv;
        if (GELU) v = 0.5f * v * (1.0f + erff(v * 0.70710678118f));
        size_t o = (size_t)(rbase + j) * N + col;
        if (resid) v += resid[o];
        r4[j] = v;
        if (OBF) outb[o] = __float2bfloat16(v);
        else     outf[o] = v;
      }
      if (VT && col >= 2 * Dv) {
        int hh = (col - 2 * Dv) >> 6, dd = (col - 2 * Dv) & 63;
        int bb = rbase >> 10, t0 = rbase & 1023;
        short4v pk = {f2bf(r4[0]), f2bf(r4[1]), f2bf(r4[2]), f2bf(r4[3])};
        *(short4v*)(vt + (((size_t)(bb * Hv + hh) * HDv + dd) << 10) + t0) = pk;
      }
    }
  }
}

__global__ __launch_bounds__(256) void qkv_gemm_kernel(const __hip_bfloat16* A,
                                                       const __hip_bfloat16* Wt,
                                                       const float* bias,
                                                       void* outv, __hip_bfloat16* vt,
                                                       int M, int N, int K) {
  gemm128_body<false, true, true>(A, Wt, bias, nullptr, outv, vt, M, N, K);
}
__global__ __launch_bounds__(256) void fc_gemm_kernel(const __hip_bfloat16* A,
                                                      const __hip_bfloat16* Wt,
                                                      const float* bias,
                                                      void* outv, int M, int N, int K) {
  gemm128_body<true, true, false>(A, Wt, bias, nullptr, outv, nullptr, M, N, K);
}

// ---------------- 64x64 MFMA GEMM body (BK=64, swizzled, 2-phase dbuf) -----
__device__ __forceinline__ void gemm64_body(const __hip_bfloat16* __restrict__ A,
                                            const __hip_bfloat16* __restrict__ Wt,
                                            const float* __restrict__ bias,
                                            const float* __restrict__ resid,
                                            float* __restrict__ out,
                                            int M, int N, int K) {
  __shared__ short As[2][4096];
  __shared__ short Bs[2][4096];
  int nwg = gridDim.x * gridDim.y;
  int wgid = xcd_remap(blockIdx.y * gridDim.x + blockIdx.x, nwg);
  int m0 = (wgid % gridDim.x) * 64, n0 = (wgid / gridDim.x) * 64;

  int tid = threadIdx.x;
  int w = tid >> 6, lane = tid & 63;
  int wr = w >> 1, wc = w & 1;
  int lr = lane & 15, lk = lane >> 4;
  int rsub = lane >> 3, go = lane & 7;

  f32x4 acc[2][2];
  #pragma unroll
  for (int m = 0; m < 2; ++m)
    #pragma unroll
    for (int n = 0; n < 2; ++n) acc[m][n] = (f32x4){0.f, 0.f, 0.f, 0.f};

  auto stg = [&](int k0, int p) {
    #pragma unroll
    for (int e = 0; e < 2; ++e) {
      int row = w * 16 + e * 8 + rsub;
      int gs = (go ^ rsub) * 8;
      gld16(A  + (size_t)(m0 + row) * K + k0 + gs, &As[p][w * 1024 + e * 512]);
      gld16(Wt + (size_t)(n0 + row) * K + k0 + gs, &Bs[p][w * 1024 + e * 512]);
    }
  };

  stg(0, 0);
  __syncthreads();
  int NK = K >> 6;
  for (int kt = 0; kt < NK; ++kt) {
    int p = kt & 1;
    if (kt + 1 < NK) stg((kt + 1) << 6, p ^ 1);
    #pragma unroll
    for (int kf = 0; kf < 2; ++kf) {
      bf16x8 af[2], bf[2];
      #pragma unroll
      for (int m = 0; m < 2; ++m) {
        int row = wr * 32 + m * 16 + lr;
        af[m] = *(const bf16x8*)(&As[p][row * 64 + (((kf * 4 + lk) ^ (row & 7)) * 8)]);
      }
      #pragma unroll
      for (int n = 0; n < 2; ++n) {
        int row = wc * 32 + n * 16 + lr;
        bf[n] = *(const bf16x8*)(&Bs[p][row * 64 + (((kf * 4 + lk) ^ (row & 7)) * 8)]);
      }
      #pragma unroll
      for (int m = 0; m < 2; ++m)
        #pragma unroll
        for (int n = 0; n < 2; ++n)
          acc[m][n] = __builtin_amdgcn_mfma_f32_16x16x32_bf16(af[m], bf[n], acc[m][n], 0, 0, 0);
    }
    __syncthreads();
  }

  int row0 = m0 + wr * 32, col0 = n0 + wc * 32;
  #pragma unroll
  for (int n = 0; n < 2; ++n) {
    int col = col0 + n * 16 + lr;
    float bv = bias ? bias[col] : 0.f;
    #pragma unroll
    for (int m = 0; m < 2; ++m) {
      int rbase = row0 + m * 16 + lk * 4;
      #pragma unroll
      for (int j = 0; j < 4; ++j) {
        float v = acc[m][n][j] + bv;
        size_t o = (size_t)(rbase + j) * N + col;
        if (resid) v += resid[o];
        out[o] = v;
      }
    }
  }
}

__global__ __launch_bounds__(256) void proj_gemm_kernel(const __hip_bfloat16* A,
                                                        const __hip_bfloat16* Wt,
                                                        const float* bias,
                                                        const float* resid, float* out,
                                                        int M, int N, int K) {
  gemm64_body(A, Wt, bias, resid, out, M, N, K);
}
__global__ __launch_bounds__(256) void fcproj_gemm_kernel(const __hip_bfloat16* A,
                                                          const __hip_bfloat16* Wt,
                                                          const float* bias,
                                                          const float* resid, float* out,
                                                          int M, int N, int K) {
  gemm64_body(A, Wt, bias, resid, out, M, N, K);
}

// ---------------- 256x256 8-phase counted-vmcnt GEMM (head) ---------------
// REVERTED to the round-6 (passing) schedule: prologue vmcnt(4)+barrier, loop
// vmcnt(4). Invariant: each half's per-wave retire happens >=1 phase (with a
// barrier) before its first read. vmcnt(6) violated this (same-phase retire/
// read, no publication barrier -> cross-wave race, round-7 failure).
__global__ __launch_bounds__(512, 2) void gemm256_kernel(const __hip_bfloat16* __restrict__ A,
                                                         const __hip_bfloat16* __restrict__ Wt,
                                                         float* __restrict__ out,
                                                         int N, int K) {
  __shared__ short lds[65536];   // 128 KB
  int nwg = gridDim.x * gridDim.y;
  int wgid = xcd_remap(blockIdx.y * gridDim.x + blockIdx.x, nwg);
  int m0 = (wgid % gridDim.x) * 256, n0 = (wgid / gridDim.x) * 256;

  int tid = threadIdx.x;
  int w = tid >> 6, lane = tid & 63;
  int wr = w >> 2, wc = w & 3;          // 2 x 4 waves
  int lr = lane & 15, lk = lane >> 4;

  f32x4 acc[8][4];
  #pragma unroll
  for (int m = 0; m < 8; ++m)
    #pragma unroll
    for (int n = 0; n < 4; ++n) acc[m][n] = (f32x4){0.f, 0.f, 0.f, 0.f};

  int NT = K >> 6;

  // half h: 0 = A rows 0-127, 1 = B rows 0-127, 2 = B rows 128-255, 3 = A rows 128-255
  auto stage = [&](int tau, int h) {
    int tsrc = tau < NT ? tau : NT - 1;       // phantom: re-read last tile
    const __hip_bfloat16* mat;
    size_t rb; int lofs;
    if (h == 0)      { mat = A;  rb = (size_t)m0;       lofs = 0; }
    else if (h == 1) { mat = Wt; rb = (size_t)n0;       lofs = 16384; }
    else if (h == 2) { mat = Wt; rb = (size_t)n0 + 128; lofs = 24576; }
    else             { mat = A;  rb = (size_t)m0 + 128; lofs = 8192; }
    short* lb = lds + (tau & 1) * 32768 + lofs;   // parity of REQUESTED tile
    #pragma unroll
    for (int e = 0; e < 2; ++e) {
      int idx = e * 512 + tid;
      int r = idx >> 3, g = idx & 7;
      gld16(mat + (rb + r) * (size_t)K + tsrc * 64 + ((g ^ (r & 7)) * 8), lb + idx * 8);
    }
  };

  // prologue: tile 0 staged; A0,B0 retired + published before first reads
  stage(0, 0); stage(0, 1); stage(0, 2); stage(0, 3);
  asm volatile("s_waitcnt vmcnt(4)" ::: "memory");
  asm volatile("s_barrier" ::: "memory");

  for (int tau = 0; tau < NT; ++tau) {
    const short* bufA = lds + (tau & 1) * 32768;
    const short* bufB = bufA + 16384;
    #pragma unroll
    for (int q = 0; q < 4; ++q) {
      stage(tau + 1, q);
      asm volatile("s_waitcnt vmcnt(4)" ::: "memory");
      int qm = q >> 1, qn = q & 1;
      const short* ab = bufA + qm * 8192;
      const short* bb = bufB + qn * 8192;
      bf16x8 af[4][2], bf[2][2];
      #pragma unroll
      for (int mi = 0; mi < 4; ++mi) {
        int ra = wr * 64 + mi * 16 + lr;
        #pragma unroll
        for (int kf = 0; kf < 2; ++kf)
          af[mi][kf] = *(const bf16x8*)(ab + ra * 64 + (((kf * 4 + lk) ^ (ra & 7)) * 8));
      }
      #pragma unroll
      for (int ni = 0; ni < 2; ++ni) {
        int rb2 = wc * 32 + ni * 16 + lr;
        #pragma unroll
        for (int kf = 0; kf < 2; ++kf)
          bf[ni][kf] = *(const bf16x8*)(bb + rb2 * 64 + (((kf * 4 + lk) ^ (rb2 & 7)) * 8));
      }
      asm volatile("s_barrier" ::: "memory");
      __builtin_amdgcn_s_setprio(1);
      #pragma unroll
      for (int mi = 0; mi < 4; ++mi)
        #pragma unroll
        for (int ni = 0; ni < 2; ++ni)
          #pragma unroll
          for (int kf = 0; kf < 2; ++kf)
            acc[qm * 4 + mi][qn * 2 + ni] = __builtin_amdgcn_mfma_f32_16x16x32_bf16(
                af[mi][kf], bf[ni][kf], acc[qm * 4 + mi][qn * 2 + ni], 0, 0, 0);
      __builtin_amdgcn_s_setprio(0);
      asm volatile("s_barrier" ::: "memory");
    }
  }

  #pragma unroll
  for (int gm = 0; gm < 8; ++gm) {
    int row = m0 + (gm >> 2) * 128 + wr * 64 + (gm & 3) * 16 + lk * 4;
    #pragma unroll
    for (int gn = 0; gn < 4; ++gn) {
      int col = n0 + (gn >> 1) * 128 + wc * 32 + (gn & 1) * 16 + lr;
      #pragma unroll
      for (int j = 0; j < 4; ++j)
        out[(size_t)(row + j) * N + col] = acc[gm][gn][j];
    }
  }
}

// ---------------- MFMA flash attention (K/V dbuf + setprio) ----------------
__global__ __launch_bounds__(256) void attn_kernel(const __hip_bfloat16* __restrict__ qkv,
                                                   const __hip_bfloat16* __restrict__ vt,
                                                   __hip_bfloat16* __restrict__ y) {
  __shared__ short Ks[2][4096];
  __shared__ short Vts[2][4096];
  __shared__ short Ps[4][1024];
  int b = blockIdx.z, h = blockIdx.y;
  int qb = (gridDim.x - 1 - blockIdx.x) * 64;
  int tid = threadIdx.x;
  int w = tid >> 6, l = tid & 63;
  int lr = l & 15, lk = l >> 4;

  bf16x8 aq[2];
  {
    const __hip_bfloat16* qp = qkv + ((size_t)(b * Tv + qb + w * 16 + lr)) * 3 * Dv + h * HDv + lk * 8;
    aq[0] = *(const bf16x8*)qp;
    aq[1] = *(const bf16x8*)(qp + 32);
  }

  f32x4 o[4];
  #pragma unroll
  for (int n = 0; n < 4; ++n) o[n] = (f32x4){0.f, 0.f, 0.f, 0.f};
  float mrow[4] = {-1e30f, -1e30f, -1e30f, -1e30f};
  float lrow[4] = {0.f, 0.f, 0.f, 0.f};

  int r8 = l >> 3, c8 = l & 7;
  int nt = qb / 64 + 1;

  auto stageKV = [&](int kt2, int p) {
    int kbase = kt2 * 64;
    #pragma unroll
    for (int e = 0; e < 2; ++e) {
      int r0 = w * 16 + e * 8;
      int rK = r0 + r8;
      int csK = c8 ^ (rK & 7);
      gld16(qkv + ((size_t)(b * Tv + kbase + rK)) * 3 * Dv + Dv + h * HDv + csK * 8,
            &Ks[p][r0 * 64]);
      gld16(vt + ((size_t)((b * Hv + h) * HDv + rK)) * Tv + kbase + csK * 8,
            &Vts[p][r0 * 64]);
    }
  };

  stageKV(0, 0);
  __syncthreads();

  for (int kt = 0; kt < nt; ++kt) {
    int p = kt & 1;
    if (kt + 1 < nt) stageKV(kt + 1, p ^ 1);

    f32x4 s[4];
    #pragma unroll
    for (int n = 0; n < 4; ++n) s[n] = (f32x4){0.f, 0.f, 0.f, 0.f};
    __builtin_amdgcn_s_setprio(1);
    #pragma unroll
    for (int kf = 0; kf < 2; ++kf)
      #pragma unroll
      for (int nf = 0; nf < 4; ++nf) {
        int row = nf * 16 + lr;
        int g = (kf * 4 + lk) ^ (row & 7);
        bf16x8 bk = *(const bf16x8*)(&Ks[p][row * 64 + g * 8]);
        s[nf] = __builtin_amdgcn_mfma_f32_16x16x32_bf16(aq[kf], bk, s[nf], 0, 0, 0);
      }
    __builtin_amdgcn_s_setprio(0);
    #pragma unroll
    for (int nf = 0; nf < 4; ++nf)
      #pragma unroll
      for (int j = 0; j < 4; ++j) s[nf][j] *= 0.125f;

    if (kt == nt - 1) {
      #pragma unroll
      for (int nf = 0; nf < 4; ++nf) {
        int kl = nf * 16 + lr;
        #pragma unroll
        for (int j = 0; j < 4; ++j)
          if (kl > w * 16 + lk * 4 + j) s[nf][j] = -1e30f;
      }
    }

    float sc[4];
    #pragma unroll
    for (int j = 0; j < 4; ++j) {
      float pm = fmaxf(fmaxf(s[0][j], s[1][j]), fmaxf(s[2][j], s[3][j]));
      pm = fmaxf(pm, __shfl_xor(pm, 1, 64));
      pm = fmaxf(pm, __shfl_xor(pm, 2, 64));
      pm = fmaxf(pm, __shfl_xor(pm, 4, 64));
      pm = fmaxf(pm, __shfl_xor(pm, 8, 64));
      float mn = fmaxf(mrow[j], pm);
      sc[j] = __expf(mrow[j] - mn);
      mrow[j] = mn;
    }
    #pragma unroll
    for (int j = 0; j < 4; ++j) {
      float ls = 0.f;
      #pragma unroll
      for (int nf = 0; nf < 4; ++nf) {
        float p2 = __expf(s[nf][j] - mrow[j]);
        s[nf][j] = p2;
        ls += p2;
      }
      ls += __shfl_xor(ls, 1, 64);
      ls += __shfl_xor(ls, 2, 64);
      ls += __shfl_xor(ls, 4, 64);
      ls += __shfl_xor(ls, 8, 64);
      lrow[j] = lrow[j] * sc[j] + ls;
    }
    #pragma unroll
    for (int n = 0; n < 4; ++n)
      #pragma unroll
      for (int j = 0; j < 4; ++j) o[n][j] *= sc[j];

    short* pw = Ps[w];
    #pragma unroll
    for (int nf = 0; nf < 4; ++nf)
      #pragma unroll
      for (int j = 0; j < 4; ++j) {
        int ql = lk * 4 + j, k = nf * 16 + lr;
        pw[ql * 64 + (((k >> 3) ^ (ql & 7)) * 8) + (k & 7)] = f2bf(s[nf][j]);
      }
    bf16x8 pa[2];
    #pragma unroll
    for (int kf = 0; kf < 2; ++kf) {
      int g = (kf * 4 + lk) ^ (lr & 7);
      pa[kf] = *(const bf16x8*)(pw + lr * 64 + g * 8);
    }
    __builtin_amdgcn_s_setprio(1);
    #pragma unroll
    for (int kf = 0; kf < 2; ++kf)
      #pragma unroll
      for (int nf = 0; nf < 4; ++nf) {
        int d = nf * 16 + lr;
        int g = (kf * 4 + lk) ^ (d & 7);
        bf16x8 bv = *(const bf16x8*)(&Vts[p][d * 64 + g * 8]);
        o[nf] = __builtin_amdgcn_mfma_f32_16x16x32_bf16(pa[kf], bv, o[nf], 0, 0, 0);
      }
    __builtin_amdgcn_s_setprio(0);
    __syncthreads();   // drains next-tile stage + WAR for buf p
  }

  #pragma unroll
  for (int j = 0; j < 4; ++j) lrow[j] = 1.f / lrow[j];
  #pragma unroll
  for (int nf = 0; nf < 4; ++nf)
    #pragma unroll
    for (int j = 0; j < 4; ++j) {
      size_t oidx = ((size_t)(b * Tv + qb + w * 16 + lk * 4 + j)) * Dv + h * HDv + nf * 16 + lr;
      y[oidx] = __float2bfloat16(o[nf][j] * lrow[j]);
    }
}

extern "C" void kernel_launch(void* const* d_in, const int* in_sizes, int n_in,
                              void* d_out, int out_size, void* d_ws, size_t ws_size,
                              hipStream_t stream) {
  const int*   idx      = (const int*)  d_in[0];
  const float* wte      = (const float*)d_in[1];
  const float* wpe      = (const float*)d_in[2];
  const float* ln1_w    = (const float*)d_in[3];
  const float* ln1_b    = (const float*)d_in[4];
  const float* attn_w   = (const float*)d_in[5];
  const float* attn_b   = (const float*)d_in[6];
  const float* proj_w   = (const float*)d_in[7];
  const float* proj_b   = (const float*)d_in[8];
  const float* ln2_w    = (const float*)d_in[9];
  const float* ln2_b    = (const float*)d_in[10];
  const float* fc_w     = (const float*)d_in[11];
  const float* fc_b     = (const float*)d_in[12];
  const float* fcproj_w = (const float*)d_in[13];
  const float* fcproj_b = (const float*)d_in[14];
  const float* lnf_w    = (const float*)d_in[15];
  const float* lnf_b    = (const float*)d_in[16];
  const float* head_w   = (const float*)d_in[17];
  float* outp = (float*)d_out;

  char* w8 = (char*)d_ws;
  float*          x    = (float*)w8;                          // 2048*768 f32
  __hip_bfloat16* h    = (__hip_bfloat16*)(w8 + 6291456);     // 2048*768 bf16
  __hip_bfloat16* qkv  = (__hip_bfloat16*)(w8 + 9437184);     // 2048*2304 bf16
  __hip_bfloat16* m4   = qkv;                                 // 2048*3072 bf16 alias
  __hip_bfloat16* y    = (__hip_bfloat16*)(w8 + 22020096);    // 2048*768 bf16
  __hip_bfloat16* vt   = (__hip_bfloat16*)(w8 + 25165824);    // B*H*64*1024 bf16
  __hip_bfloat16* wbuf = (__hip_bfloat16*)(w8 + 28311552);    // weight staging

  __hip_bfloat16* wb_attn   = wbuf;
  __hip_bfloat16* wb_proj   = wb_attn + (size_t)768 * 2304;
  __hip_bfloat16* wb_fc     = wb_proj + (size_t)768 * 768;
  __hip_bfloat16* wb_fcproj = wb_fc   + (size_t)768 * 3072;

  embed_kernel<<<(MROWS * Dv / 4 + 255) / 256, 256, 0, stream>>>(idx, wte, wpe, x);

  for (int l = 0; l < Lv; ++l) {
    ln_kernel<<<MROWS, 256, 0, stream>>>(x, ln1_w + (size_t)l * Dv, ln1_b + (size_t)l * Dv, h);

    tcast4_kernel<<<6912, 256, 0, stream>>>(
        attn_w   + (size_t)l * Dv * 3 * Dv,
        proj_w   + (size_t)l * Dv * Dv,
        fc_w     + (size_t)l * Dv * 4 * Dv,
        fcproj_w + (size_t)l * 4 * Dv * Dv,
        wb_attn, wb_proj, wb_fc, wb_fcproj);

    qkv_gemm_kernel<<<dim3(MROWS / 128, 3 * Dv / 128), 256, 0, stream>>>(
        h, wb_attn, attn_b + (size_t)l * 3 * Dv, qkv, vt, MROWS, 3 * Dv, Dv);

    attn_kernel<<<dim3(Tv / 64, Hv, Bv), 256, 0, stream>>>(qkv, vt, y);

    proj_gemm_kernel<<<dim3(MROWS / 64, Dv / 64), 256, 0, stream>>>(
        y, wb_proj, proj_b + (size_t)l * Dv, x, x, MROWS, Dv, Dv);

    ln_kernel<<<MROWS, 256, 0, stream>>>(x, ln2_w + (size_t)l * Dv, ln2_b + (size_t)l * Dv, h);

    fc_gemm_kernel<<<dim3(MROWS / 128, 4 * Dv / 128), 256, 0, stream>>>(
        h, wb_fc, fc_b + (size_t)l * 4 * Dv, m4, MROWS, 4 * Dv, Dv);

    fcproj_gemm_kernel<<<dim3(MROWS / 64, Dv / 64), 256, 0, stream>>>(
        m4, wb_fcproj, fcproj_b + (size_t)l * Dv, x, x, MROWS, Dv, 4 * Dv);
  }

  ln_kernel<<<MROWS, 256, 0, stream>>>(x, lnf_w, lnf_b, h);
  tcast_kernel<<<dim3(Vv / 32, Dv / 32), 256, 0, stream>>>(head_w, wbuf, Dv, Vv);
  gemm256_kernel<<<dim3(MROWS / 256, Vv / 256), 512, 0, stream>>>(
      h, wbuf, outp, Vv, Dv);
}